// Round 6
// baseline (309.595 us; speedup 1.0000x reference)
//
#include <hip/hip_runtime.h>
#include <math.h>

#define NN 40000
#define EE 640000
#define NG 64
#define SCAN_BLOCKS ((NN + 1023) / 1024)

__device__ __forceinline__ float eluf(float x) { return x > 0.f ? x : expm1f(x); }

typedef const __attribute__((address_space(1))) char gas_char;
typedef __attribute__((address_space(3))) char las_char;

__device__ __forceinline__ void async_copy16(void* l, const void* g) {
  __builtin_amdgcn_global_load_lds((gas_char*)g, (las_char*)l, 16, 0, 0);
}

__device__ __forceinline__ unsigned f2bf(float x) {  // RNE f32->bf16 (no NaN inputs)
  unsigned u = __float_as_uint(x);
  return (u + 0x7fffu + ((u >> 16) & 1u)) >> 16;
}
__device__ __forceinline__ unsigned packbf(float lo, float hi) {
  return f2bf(lo) | (f2bf(hi) << 16);
}
__device__ __forceinline__ float bflo(unsigned p) { return __uint_as_float(p << 16); }
__device__ __forceinline__ float bfhi(unsigned p) { return __uint_as_float(p & 0xffff0000u); }

__global__ void zero_int_kernel(int* __restrict__ p, int n) {
  int i = blockIdx.x * 256 + threadIdx.x;
  if (i < n) p[i] = 0;
}

__global__ void count_deg_kernel(const int* __restrict__ dst, int* __restrict__ deg, int e) {
  int i = blockIdx.x * 256 + threadIdx.x;
  if (i < e) atomicAdd(&deg[dst[i]], 1);
}

__global__ __launch_bounds__(1024) void scanA_kernel(const int* __restrict__ deg,
                                                     int* __restrict__ row_ptr,
                                                     int* __restrict__ bsum, int n) {
  __shared__ int wsum[16];
  int t = threadIdx.x, lane = t & 63, wid = t >> 6;
  int i = blockIdx.x * 1024 + t;
  int v = (i < n) ? deg[i] : 0;
#pragma unroll
  for (int off = 1; off < 64; off <<= 1) {
    int u = __shfl_up(v, off);
    if (lane >= off) v += u;
  }
  if (lane == 63) wsum[wid] = v;
  __syncthreads();
  if (t < 16) {
    int w = wsum[t];
#pragma unroll
    for (int off = 1; off < 16; off <<= 1) {
      int u = __shfl_up(w, off);
      if (t >= off) w += u;
    }
    wsum[t] = w;
  }
  __syncthreads();
  if (wid > 0) v += wsum[wid - 1];
  if (i < n) row_ptr[i + 1] = v;
  if (t == 1023) bsum[blockIdx.x] = v;
}

__global__ void scanB_kernel(const int* __restrict__ bsum, int* __restrict__ boff, int nb) {
  int lane = threadIdx.x;
  int v = (lane < nb) ? bsum[lane] : 0;
  int orig = v;
#pragma unroll
  for (int off = 1; off < 64; off <<= 1) {
    int u = __shfl_up(v, off);
    if (lane >= off) v += u;
  }
  if (lane < nb) boff[lane] = v - orig;
}

__global__ __launch_bounds__(1024) void scanC_kernel(int* __restrict__ row_ptr,
                                                     const int* __restrict__ boff,
                                                     int* __restrict__ cursor, int n) {
  int i = blockIdx.x * 1024 + threadIdx.x;
  if (i < n) {
    int v = row_ptr[i + 1] + boff[i >> 10];
    row_ptr[i + 1] = v;
    if (i + 1 < n) cursor[i + 1] = v;
    if (i == 0) { cursor[0] = 0; row_ptr[0] = 0; }
  }
}

__global__ void scatter_kernel(const int* __restrict__ src, const int* __restrict__ dst,
                               int* __restrict__ cursor, int* __restrict__ csr_src, int e) {
  int i = blockIdx.x * 256 + threadIdx.x;
  if (i < e) {
    int d = dst[i];
    int pos = atomicAdd(&cursor[d], 1);
    csr_src[pos] = src[i];
  }
}

// GEMM (K=128, OUT=128): h = x @ W written as PACKED BF16 pairs
// hb[row*64 + j] = (bf16(h[row][j]), bf16(h[row][j+64])), plus fused als/ald.
__global__ __launch_bounds__(256, 2) void gemm128_kernel(
    const float* __restrict__ x, const float* __restrict__ W,
    const float* __restrict__ a_s, const float* __restrict__ a_d,
    unsigned* __restrict__ hb, float* __restrict__ als, float* __restrict__ ald)
{
  __shared__ float xs[64 * 128];
  __shared__ float ws[2][32 * 128];

  int t = threadIdx.x;
  int row0 = blockIdx.x * 64;

  {
    const char* xg = (const char*)(x + (size_t)row0 * 128);
    char* xl = (char*)xs;
#pragma unroll
    for (int it = 0; it < 8; ++it)
      async_copy16(xl + it * 4096 + t * 16, xg + it * 4096 + t * 16);
  }
  {
    const char* wg = (const char*)W;
    char* wl = (char*)ws[0];
#pragma unroll
    for (int p = 0; p < 4; ++p)
      async_copy16(wl + p * 4096 + t * 16, wg + p * 4096 + t * 16);
  }
  __syncthreads();

  int cg = t & 31, rg = t >> 5;
  int r0 = rg * 8;
  int jlo = 2 * cg;

  float acc[8][4];
#pragma unroll
  for (int r = 0; r < 8; ++r)
#pragma unroll
    for (int c = 0; c < 4; ++c) acc[r][c] = 0.f;

  for (int ch = 0; ch < 4; ++ch) {
    if (ch < 3) {
      const char* wg = (const char*)W + (size_t)(ch + 1) * 32 * 128 * 4;
      char* wl = (char*)ws[(ch + 1) & 1];
#pragma unroll
      for (int p = 0; p < 4; ++p)
        async_copy16(wl + p * 4096 + t * 16, wg + p * 4096 + t * 16);
    }
    const float* wc = ws[ch & 1];
    const float* xc = xs + ch * 32;
#pragma unroll
    for (int kk = 0; kk < 32; kk += 4) {
      float2 wlo[4], whi[4];
#pragma unroll
      for (int q = 0; q < 4; ++q) {
        wlo[q] = *reinterpret_cast<const float2*>(&wc[(kk + q) * 128 + jlo]);
        whi[q] = *reinterpret_cast<const float2*>(&wc[(kk + q) * 128 + 64 + jlo]);
      }
#pragma unroll
      for (int r = 0; r < 8; ++r) {
        float4 xv = *reinterpret_cast<const float4*>(&xc[(r0 + r) * 128 + kk]);
        float a0 = acc[r][0], a1 = acc[r][1], a2 = acc[r][2], a3 = acc[r][3];
        a0 = fmaf(xv.x, wlo[0].x, a0); a1 = fmaf(xv.x, wlo[0].y, a1);
        a2 = fmaf(xv.x, whi[0].x, a2); a3 = fmaf(xv.x, whi[0].y, a3);
        a0 = fmaf(xv.y, wlo[1].x, a0); a1 = fmaf(xv.y, wlo[1].y, a1);
        a2 = fmaf(xv.y, whi[1].x, a2); a3 = fmaf(xv.y, whi[1].y, a3);
        a0 = fmaf(xv.z, wlo[2].x, a0); a1 = fmaf(xv.z, wlo[2].y, a1);
        a2 = fmaf(xv.z, whi[2].x, a2); a3 = fmaf(xv.z, whi[2].y, a3);
        a0 = fmaf(xv.w, wlo[3].x, a0); a1 = fmaf(xv.w, wlo[3].y, a1);
        a2 = fmaf(xv.w, whi[3].x, a2); a3 = fmaf(xv.w, whi[3].y, a3);
        acc[r][0] = a0; acc[r][1] = a1; acc[r][2] = a2; acc[r][3] = a3;
      }
    }
    __syncthreads();
  }

#pragma unroll
  for (int r = 0; r < 8; ++r) {
    uint2 pv;
    pv.x = packbf(acc[r][0], acc[r][2]);
    pv.y = packbf(acc[r][1], acc[r][3]);
    *reinterpret_cast<uint2*>(&hb[(size_t)(row0 + r0 + r) * 64 + jlo]) = pv;
  }

  float as0 = a_s[jlo], as1 = a_s[jlo + 1], as2 = a_s[jlo + 64], as3 = a_s[jlo + 65];
  float ad0 = a_d[jlo], ad1 = a_d[jlo + 1], ad2 = a_d[jlo + 64], ad3 = a_d[jlo + 65];
  int lane = t & 63;
#pragma unroll
  for (int r = 0; r < 8; ++r) {
    float psa = fmaf(acc[r][0], as0, acc[r][1] * as1);
    float psb = fmaf(acc[r][2], as2, acc[r][3] * as3);
    float pda = fmaf(acc[r][0], ad0, acc[r][1] * ad1);
    float pdb = fmaf(acc[r][2], ad2, acc[r][3] * ad3);
#pragma unroll
    for (int m = 1; m < 16; m <<= 1) {
      psa += __shfl_xor(psa, m); psb += __shfl_xor(psb, m);
      pda += __shfl_xor(pda, m); pdb += __shfl_xor(pdb, m);
    }
    if ((lane & 15) == 0) {
      int hA = (lane >> 4) & 1;
      size_t row = (size_t)(row0 + r0 + r);
      als[row * 4 + hA] = psa; als[row * 4 + hA + 2] = psb;
      ald[row * 4 + hA] = pda; ald[row * 4 + hA + 2] = pdb;
    }
  }
}

// GEMM (K=128, OUT=32) f32 out, fused single-head als/ald.
__global__ __launch_bounds__(256, 2) void gemm32_kernel(
    const float* __restrict__ x, const float* __restrict__ W,
    const float* __restrict__ a_s, const float* __restrict__ a_d,
    float* __restrict__ h, float* __restrict__ als, float* __restrict__ ald)
{
  __shared__ float xs[64 * 128];
  __shared__ float ws[2][32 * 32];
  int t = threadIdx.x;
  int row0 = blockIdx.x * 64;
  {
    const char* xg = (const char*)(x + (size_t)row0 * 128);
    char* xl = (char*)xs;
#pragma unroll
    for (int it = 0; it < 8; ++it)
      async_copy16(xl + it * 4096 + t * 16, xg + it * 4096 + t * 16);
  }
  async_copy16((char*)ws[0] + t * 16, (const char*)W + t * 16);
  __syncthreads();

  int cg = t & 7, rg = t >> 3;
  int r0 = rg * 2, c0 = cg * 4;
  float acc[2][4];
#pragma unroll
  for (int r = 0; r < 2; ++r)
#pragma unroll
    for (int c = 0; c < 4; ++c) acc[r][c] = 0.f;

  for (int ch = 0; ch < 4; ++ch) {
    if (ch < 3) {
      const char* wg = (const char*)W + (size_t)(ch + 1) * 32 * 32 * 4;
      async_copy16((char*)ws[(ch + 1) & 1] + t * 16, wg + t * 16);
    }
    const float* wc = ws[ch & 1];
    const float* xc = xs + ch * 32;
#pragma unroll
    for (int kk = 0; kk < 32; kk += 4) {
      float4 wv[4];
#pragma unroll
      for (int q = 0; q < 4; ++q)
        wv[q] = *reinterpret_cast<const float4*>(&wc[(kk + q) * 32 + c0]);
#pragma unroll
      for (int r = 0; r < 2; ++r) {
        float4 xv = *reinterpret_cast<const float4*>(&xc[(r0 + r) * 128 + kk]);
#pragma unroll
        for (int c = 0; c < 4; ++c) {
          float a = acc[r][c];
          a = fmaf(xv.x, (&wv[0].x)[c], a);
          a = fmaf(xv.y, (&wv[1].x)[c], a);
          a = fmaf(xv.z, (&wv[2].x)[c], a);
          a = fmaf(xv.w, (&wv[3].x)[c], a);
          acc[r][c] = a;
        }
      }
    }
    __syncthreads();
  }

#pragma unroll
  for (int r = 0; r < 2; ++r) {
    float4 hv = make_float4(acc[r][0], acc[r][1], acc[r][2], acc[r][3]);
    *reinterpret_cast<float4*>(&h[(size_t)(row0 + r0 + r) * 32 + c0]) = hv;
  }
  float asv[4], adv[4];
#pragma unroll
  for (int c = 0; c < 4; ++c) { asv[c] = a_s[c0 + c]; adv[c] = a_d[c0 + c]; }
#pragma unroll
  for (int r = 0; r < 2; ++r) {
    float ps = acc[r][0] * asv[0] + acc[r][1] * asv[1] + acc[r][2] * asv[2] + acc[r][3] * asv[3];
    float pd = acc[r][0] * adv[0] + acc[r][1] * adv[1] + acc[r][2] * adv[2] + acc[r][3] * adv[3];
#pragma unroll
    for (int m = 1; m < 8; m <<= 1) { ps += __shfl_xor(ps, m); pd += __shfl_xor(pd, m); }
    if ((t & 7) == 0) {
      als[row0 + r0 + r] = ps;
      ald[row0 + r0 + r] = pd;
    }
  }
}

// Aggregate for OUT=128 (4 heads x 32), packed-bf16 h gather.
// One wave per dst node. Half-wave edge split + unroll x4 (4 loads in flight
// per lane). s_src holds s<<5 (uint2 index); s_ex2[j][hsel] = (ex[h], ex[h+2]).
__global__ __launch_bounds__(256) void aggregate128_kernel(
    const unsigned* __restrict__ hb, const float* __restrict__ als, const float* __restrict__ ald,
    const int* __restrict__ row_ptr, const int* __restrict__ csr_src,
    const float* __restrict__ bias, const float* __restrict__ ln_g, const float* __restrict__ ln_b,
    float* __restrict__ out, int n)
{
  __shared__ int s_src[4][64];
  __shared__ float2 s_ex2[4][64][2];
  int t = threadIdx.x, lane = t & 63, wid = t >> 6;
  int node = blockIdx.x * 4 + wid;
  if (node >= n) return;
  int start = row_ptr[node], end = row_ptr[node + 1];
  int deg = end - start;

  float4 adq = reinterpret_cast<const float4*>(ald)[node];
  float adl[4] = {adq.x, adq.y, adq.z, adq.w};
  int hi = lane >> 5, c = lane & 31;
  int hsel = c >> 4;            // head pair selector: features use (hsel, hsel+2)
  const uint2* hbase = reinterpret_cast<const uint2*>(hb + 2 * c);
  float a0 = 0.f, a1 = 0.f, a2 = 0.f, a3 = 0.f;   // features 2c,2c+1,2c+64,2c+65
  float ssum[4];

  if (deg <= 64) {
    // single-pass softmax: one edge per lane
    bool valid = lane < deg;
    int s = 0;
    if (valid) s = csr_src[start + lane];
    float4 q = reinterpret_cast<const float4*>(als)[s];
    float v[4] = {q.x, q.y, q.z, q.w};
    float mx[4];
#pragma unroll
    for (int hh = 0; hh < 4; ++hh) {
      float w = v[hh] + adl[hh];
      w = w > 0.f ? w : 0.2f * w;
      v[hh] = valid ? w : -INFINITY;
      mx[hh] = v[hh];
    }
#pragma unroll
    for (int hh = 0; hh < 4; ++hh)
#pragma unroll
      for (int m = 1; m < 64; m <<= 1) mx[hh] = fmaxf(mx[hh], __shfl_xor(mx[hh], m));
    float ex[4];
#pragma unroll
    for (int hh = 0; hh < 4; ++hh) {
      ex[hh] = valid ? __expf(v[hh] - mx[hh]) : 0.f;
      ssum[hh] = ex[hh];
    }
#pragma unroll
    for (int hh = 0; hh < 4; ++hh)
#pragma unroll
      for (int m = 1; m < 64; m <<= 1) ssum[hh] += __shfl_xor(ssum[hh], m);

    s_src[wid][lane] = s << 5;
    s_ex2[wid][lane][0] = make_float2(ex[0], ex[2]);
    s_ex2[wid][lane][1] = make_float2(ex[1], ex[3]);

    // half-wave split gather, unroll x4
    int d1 = deg >> 1, d0c = deg - d1;
    int base = hi ? d0c : 0;
    int cnt = hi ? d1 : d0c;
    float b0 = 0.f, b1 = 0.f, b2 = 0.f, b3 = 0.f;
    float c0a = 0.f, c1a = 0.f, c2a = 0.f, c3a = 0.f;
    float d0a = 0.f, d1a = 0.f, d2a = 0.f, d3a = 0.f;
    int j = 0;
    for (; j + 4 <= cnt; j += 4) {
      int o0 = s_src[wid][base + j];
      int o1 = s_src[wid][base + j + 1];
      int o2 = s_src[wid][base + j + 2];
      int o3 = s_src[wid][base + j + 3];
      uint2 u0 = hbase[o0], u1 = hbase[o1], u2 = hbase[o2], u3 = hbase[o3];
      float2 w0 = s_ex2[wid][base + j][hsel];
      float2 w1 = s_ex2[wid][base + j + 1][hsel];
      float2 w2 = s_ex2[wid][base + j + 2][hsel];
      float2 w3 = s_ex2[wid][base + j + 3][hsel];
      a0 = fmaf(w0.x, bflo(u0.x), a0); a1 = fmaf(w0.x, bflo(u0.y), a1);
      a2 = fmaf(w0.y, bfhi(u0.x), a2); a3 = fmaf(w0.y, bfhi(u0.y), a3);
      b0 = fmaf(w1.x, bflo(u1.x), b0); b1 = fmaf(w1.x, bflo(u1.y), b1);
      b2 = fmaf(w1.y, bfhi(u1.x), b2); b3 = fmaf(w1.y, bfhi(u1.y), b3);
      c0a = fmaf(w2.x, bflo(u2.x), c0a); c1a = fmaf(w2.x, bflo(u2.y), c1a);
      c2a = fmaf(w2.y, bfhi(u2.x), c2a); c3a = fmaf(w2.y, bfhi(u2.y), c3a);
      d0a = fmaf(w3.x, bflo(u3.x), d0a); d1a = fmaf(w3.x, bflo(u3.y), d1a);
      d2a = fmaf(w3.y, bfhi(u3.x), d2a); d3a = fmaf(w3.y, bfhi(u3.y), d3a);
    }
    for (; j < cnt; ++j) {
      int o0 = s_src[wid][base + j];
      uint2 u0 = hbase[o0];
      float2 w0 = s_ex2[wid][base + j][hsel];
      a0 = fmaf(w0.x, bflo(u0.x), a0); a1 = fmaf(w0.x, bflo(u0.y), a1);
      a2 = fmaf(w0.y, bfhi(u0.x), a2); a3 = fmaf(w0.y, bfhi(u0.y), a3);
    }
    a0 += b0 + c0a + d0a; a1 += b1 + c1a + d1a;
    a2 += b2 + c2a + d2a; a3 += b3 + c3a + d3a;
    a0 += __shfl_xor(a0, 32); a1 += __shfl_xor(a1, 32);
    a2 += __shfl_xor(a2, 32); a3 += __shfl_xor(a3, 32);
  } else {
    // generic 2-pass fallback (deg > 64: essentially never)
    float mx[4];
#pragma unroll
    for (int hh = 0; hh < 4; ++hh) mx[hh] = -INFINITY;
    for (int eb = start; eb < end; eb += 64) {
      int e = eb + lane;
      if (e < end) {
        int s = csr_src[e];
        float4 q = reinterpret_cast<const float4*>(als)[s];
        float av[4] = {q.x, q.y, q.z, q.w};
#pragma unroll
        for (int hh = 0; hh < 4; ++hh) {
          float v = av[hh] + adl[hh];
          v = v > 0.f ? v : 0.2f * v;
          mx[hh] = fmaxf(mx[hh], v);
        }
      }
    }
#pragma unroll
    for (int hh = 0; hh < 4; ++hh)
#pragma unroll
      for (int m = 1; m < 64; m <<= 1) mx[hh] = fmaxf(mx[hh], __shfl_xor(mx[hh], m));
#pragma unroll
    for (int hh = 0; hh < 4; ++hh) ssum[hh] = 0.f;
    for (int eb = start; eb < end; eb += 64) {
      int e = eb + lane;
      int s = 0;
      float exv[4] = {0.f, 0.f, 0.f, 0.f};
      if (e < end) {
        s = csr_src[e];
        float4 q = reinterpret_cast<const float4*>(als)[s];
        float av[4] = {q.x, q.y, q.z, q.w};
#pragma unroll
        for (int hh = 0; hh < 4; ++hh) {
          float v = av[hh] + adl[hh];
          v = v > 0.f ? v : 0.2f * v;
          exv[hh] = __expf(v - mx[hh]);
          ssum[hh] += exv[hh];
        }
      }
      s_src[wid][lane] = s << 5;
      s_ex2[wid][lane][0] = make_float2(exv[0], exv[2]);
      s_ex2[wid][lane][1] = make_float2(exv[1], exv[3]);
      int cnt = end - eb; if (cnt > 64) cnt = 64;
      for (int j = 0; j < cnt; ++j) {
        int o = s_src[wid][j];
        uint2 u = hbase[o];
        float2 w = s_ex2[wid][j][hsel];
        a0 = fmaf(w.x, bflo(u.x), a0); a1 = fmaf(w.x, bflo(u.y), a1);
        a2 = fmaf(w.y, bfhi(u.x), a2); a3 = fmaf(w.y, bfhi(u.y), a3);
      }
    }
#pragma unroll
    for (int hh = 0; hh < 4; ++hh)
#pragma unroll
      for (int m = 1; m < 64; m <<= 1) ssum[hh] += __shfl_xor(ssum[hh], m);
    a0 *= 0.5f; a1 *= 0.5f; a2 *= 0.5f; a3 *= 0.5f;
    a0 += __shfl_xor(a0, 32); a1 += __shfl_xor(a1, 32);
    a2 += __shfl_xor(a2, 32); a3 += __shfl_xor(a3, 32);
  }

  float2 blo = *reinterpret_cast<const float2*>(&bias[2 * c]);
  float2 bhi = *reinterpret_cast<const float2*>(&bias[2 * c + 64]);
  float is0 = 1.f / (ssum[hsel] + 1e-16f), is1 = 1.f / (ssum[hsel + 2] + 1e-16f);
  float o0 = a0 * is0 + blo.x;
  float o1 = a1 * is0 + blo.y;
  float o2 = a2 * is1 + bhi.x;
  float o3 = a3 * is1 + bhi.y;
  // LN via E[x^2]-mu^2: two co-issued reduction chains
  float red = o0 + o1 + o2 + o3;
  float sq2 = o0 * o0 + o1 * o1 + o2 * o2 + o3 * o3;
#pragma unroll
  for (int m = 1; m < 64; m <<= 1) {
    red += __shfl_xor(red, m);
    sq2 += __shfl_xor(sq2, m);
  }
  float mu = red * (1.f / 256.f);       // each feature counted twice across halves
  float var = sq2 * (1.f / 256.f) - mu * mu;
  float rstd = rsqrtf(var + 1e-5f);
  int f = 2 * c + 64 * hi;
  float2 gv = *reinterpret_cast<const float2*>(&ln_g[f]);
  float2 bv = *reinterpret_cast<const float2*>(&ln_b[f]);
  float dx = (hi ? o2 : o0) - mu, dy = (hi ? o3 : o1) - mu;
  float2 yv;
  yv.x = eluf(dx * rstd * gv.x + bv.x);
  yv.y = eluf(dy * rstd * gv.y + bv.y);
  *reinterpret_cast<float2*>(&out[(size_t)node * 128 + f]) = yv;
}

// Aggregate for OUT=32 single head (f32 h rows). Half-wave edge split,
// unroll x4; s_src holds s<<5 (float index of row).
__global__ __launch_bounds__(256) void aggregate32_kernel(
    const float* __restrict__ h, const float* __restrict__ als, const float* __restrict__ ald,
    const int* __restrict__ row_ptr, const int* __restrict__ csr_src,
    const float* __restrict__ bias, const float* __restrict__ ln_g, const float* __restrict__ ln_b,
    float* __restrict__ out, int n)
{
  __shared__ int s_src[4][64];
  __shared__ float s_ex[4][64];
  int t = threadIdx.x, lane = t & 63, wid = t >> 6;
  int node = blockIdx.x * 4 + wid;
  if (node >= n) return;
  int start = row_ptr[node], end = row_ptr[node + 1];
  int deg = end - start;
  float adl = ald[node];
  int hi = lane >> 5, col = lane & 31;
  const float* hbase = h + col;
  float acc0 = 0.f, ssum = 0.f;

  if (deg <= 64) {
    bool valid = lane < deg;
    int s = 0;
    if (valid) s = csr_src[start + lane];
    float v = als[s] + adl;
    v = v > 0.f ? v : 0.2f * v;
    v = valid ? v : -INFINITY;
    float mx = v;
#pragma unroll
    for (int m = 1; m < 64; m <<= 1) mx = fmaxf(mx, __shfl_xor(mx, m));
    float ex = valid ? __expf(v - mx) : 0.f;
    ssum = ex;
#pragma unroll
    for (int m = 1; m < 64; m <<= 1) ssum += __shfl_xor(ssum, m);
    s_src[wid][lane] = s << 5;
    s_ex[wid][lane] = ex;

    int d1 = deg >> 1, d0c = deg - d1;
    int base = hi ? d0c : 0;
    int cnt = hi ? d1 : d0c;
    float acc1 = 0.f, acc2 = 0.f, acc3 = 0.f;
    int j = 0;
    for (; j + 4 <= cnt; j += 4) {
      int o0 = s_src[wid][base + j];
      int o1 = s_src[wid][base + j + 1];
      int o2 = s_src[wid][base + j + 2];
      int o3 = s_src[wid][base + j + 3];
      float h0 = hbase[o0], h1 = hbase[o1], h2 = hbase[o2], h3 = hbase[o3];
      acc0 = fmaf(s_ex[wid][base + j], h0, acc0);
      acc1 = fmaf(s_ex[wid][base + j + 1], h1, acc1);
      acc2 = fmaf(s_ex[wid][base + j + 2], h2, acc2);
      acc3 = fmaf(s_ex[wid][base + j + 3], h3, acc3);
    }
    for (; j < cnt; ++j)
      acc0 = fmaf(s_ex[wid][base + j], hbase[s_src[wid][base + j]], acc0);
    acc0 += acc1 + acc2 + acc3;
    acc0 += __shfl_xor(acc0, 32);
  } else {
    float mx = -INFINITY;
    for (int eb = start; eb < end; eb += 64) {
      int e = eb + lane;
      if (e < end) {
        float v = als[csr_src[e]] + adl;
        v = v > 0.f ? v : 0.2f * v;
        mx = fmaxf(mx, v);
      }
    }
#pragma unroll
    for (int m = 1; m < 64; m <<= 1) mx = fmaxf(mx, __shfl_xor(mx, m));
    for (int eb = start; eb < end; eb += 64) {
      int e = eb + lane;
      int s = 0; float ex = 0.f;
      if (e < end) {
        s = csr_src[e];
        float v = als[s] + adl;
        v = v > 0.f ? v : 0.2f * v;
        ex = __expf(v - mx);
        ssum += ex;
      }
      s_src[wid][lane] = s << 5;
      s_ex[wid][lane] = ex;
      int cnt = end - eb; if (cnt > 64) cnt = 64;
      for (int j = 0; j < cnt; ++j)
        acc0 = fmaf(s_ex[wid][j], hbase[s_src[wid][j]], acc0);
    }
#pragma unroll
    for (int m = 1; m < 64; m <<= 1) ssum += __shfl_xor(ssum, m);
    acc0 *= 0.5f;
    acc0 += __shfl_xor(acc0, 32);
  }

  float o0 = acc0 / (ssum + 1e-16f) + bias[col];
  float red = o0, sq2 = o0 * o0;
#pragma unroll
  for (int m = 1; m < 64; m <<= 1) {
    red += __shfl_xor(red, m);
    sq2 += __shfl_xor(sq2, m);
  }
  float mu = red * (1.f / 64.f);
  float var = sq2 * (1.f / 64.f) - mu * mu;
  float rstd = rsqrtf(var + 1e-5f);
  float y0 = (o0 - mu) * rstd * ln_g[col] + ln_b[col];
  if (lane < 32) out[(size_t)node * 32 + col] = eluf(y0);
}

__device__ __forceinline__ int lower_bound_dev(const int* a, int n, int key) {
  int lo = 0, hi = n;
  while (lo < hi) { int mid = (lo + hi) >> 1; if (a[mid] < key) lo = mid + 1; else hi = mid; }
  return lo;
}

// Fused global mean-pool + 2-layer classifier: one block per group.
__global__ __launch_bounds__(256) void poolfc_kernel(
    const float* __restrict__ x2, const int* __restrict__ batch,
    const float* __restrict__ fc1w, const float* __restrict__ fc1b,
    const float* __restrict__ fc2w, const float* __restrict__ fc2b,
    float* __restrict__ out, int n)
{
  int g = blockIdx.x;
  int lo = lower_bound_dev(batch, n, g);
  int hi = lower_bound_dev(batch, n, g + 1);
  int t = threadIdx.x;
  int c = t & 31, r = t >> 5;
  float acc = 0.f;
  for (int i = lo + r; i < hi; i += 8) acc += x2[(size_t)i * 32 + c];
  __shared__ float red[8][32];
  __shared__ float hgl[32];
  __shared__ float zl[16];
  red[r][c] = acc;
  __syncthreads();
  if (r == 0) {
    float s = 0.f;
#pragma unroll
    for (int k = 0; k < 8; ++k) s += red[k][c];
    float cnt = (float)(hi - lo);
    hgl[c] = s / fmaxf(cnt, 1.f);
  }
  __syncthreads();
  if (t < 16) {
    float a = fc1b[t];
#pragma unroll
    for (int k = 0; k < 32; ++k) a = fmaf(hgl[k], fc1w[k * 16 + t], a);
    zl[t] = fmaxf(a, 0.f);
  }
  __syncthreads();
  if (t < 2) {
    float a = fc2b[t];
#pragma unroll
    for (int j = 0; j < 16; ++j) a = fmaf(zl[j], fc2w[j * 2 + t], a);
    out[g * 2 + t] = a;
  }
}

extern "C" void kernel_launch(void* const* d_in, const int* in_sizes, int n_in,
                              void* d_out, int out_size, void* d_ws, size_t ws_size,
                              hipStream_t stream) {
  const float* x    = (const float*)d_in[0];
  const int*   ei   = (const int*)d_in[1];
  const int*   batch= (const int*)d_in[2];
  const float* W0   = (const float*)d_in[3];
  const float* as0  = (const float*)d_in[4];
  const float* ad0  = (const float*)d_in[5];
  const float* b0   = (const float*)d_in[6];
  const float* ln0g = (const float*)d_in[7];
  const float* ln0b = (const float*)d_in[8];
  const float* W1   = (const float*)d_in[9];
  const float* as1  = (const float*)d_in[10];
  const float* ad1  = (const float*)d_in[11];
  const float* b1   = (const float*)d_in[12];
  const float* ln1g = (const float*)d_in[13];
  const float* ln1b = (const float*)d_in[14];
  const float* W2   = (const float*)d_in[15];
  const float* as2  = (const float*)d_in[16];
  const float* ad2  = (const float*)d_in[17];
  const float* b2   = (const float*)d_in[18];
  const float* ln2g = (const float*)d_in[19];
  const float* ln2b = (const float*)d_in[20];
  const float* fc1w = (const float*)d_in[21];
  const float* fc1b = (const float*)d_in[22];
  const float* fc2w = (const float*)d_in[23];
  const float* fc2b = (const float*)d_in[24];
  float* out = (float*)d_out;

  const int* srce = ei;
  const int* dste = ei + EE;

  unsigned* hb = (unsigned*)d_ws;              // N*64 packed bf16 pairs
  float* B2  = (float*)(hb + (size_t)NN * 64); // N*128
  float* als = B2 + (size_t)NN * 128;          // N*4
  float* ald = als + (size_t)NN * 4;           // N*4
  float* h2  = ald + (size_t)NN * 4;           // N*32
  float* x2  = h2 + (size_t)NN * 32;           // N*32
  int* deg      = (int*)(x2 + (size_t)NN * 32);// N
  int* row_ptr  = deg + NN;                    // N+1
  int* cursor   = row_ptr + NN + 1;            // N
  int* csr_src  = cursor + NN;                 // E
  int* bsum     = csr_src + EE;                // SCAN_BLOCKS
  int* boff     = bsum + SCAN_BLOCKS;          // SCAN_BLOCKS

  // CSR build (shared by all 3 layers)
  zero_int_kernel<<<(NN + 255) / 256, 256, 0, stream>>>(deg, NN);
  count_deg_kernel<<<(EE + 255) / 256, 256, 0, stream>>>(dste, deg, EE);
  scanA_kernel<<<SCAN_BLOCKS, 1024, 0, stream>>>(deg, row_ptr, bsum, NN);
  scanB_kernel<<<1, 64, 0, stream>>>(bsum, boff, SCAN_BLOCKS);
  scanC_kernel<<<SCAN_BLOCKS, 1024, 0, stream>>>(row_ptr, boff, cursor, NN);
  scatter_kernel<<<(EE + 255) / 256, 256, 0, stream>>>(srce, dste, cursor, csr_src, EE);

  // layer 0
  gemm128_kernel<<<625, 256, 0, stream>>>(x, W0, as0, ad0, hb, als, ald);
  aggregate128_kernel<<<(NN + 3) / 4, 256, 0, stream>>>(hb, als, ald, row_ptr, csr_src,
                                                        b0, ln0g, ln0b, B2, NN);
  // layer 1
  gemm128_kernel<<<625, 256, 0, stream>>>(B2, W1, as1, ad1, hb, als, ald);
  aggregate128_kernel<<<(NN + 3) / 4, 256, 0, stream>>>(hb, als, ald, row_ptr, csr_src,
                                                        b1, ln1g, ln1b, B2, NN);
  // layer 2
  gemm32_kernel<<<625, 256, 0, stream>>>(B2, W2, as2, ad2, h2, als, ald);
  aggregate32_kernel<<<(NN + 3) / 4, 256, 0, stream>>>(h2, als, ald, row_ptr, csr_src,
                                                       b2, ln2g, ln2b, x2, NN);
  // pool + classifier (fused)
  poolfc_kernel<<<NG, 256, 0, stream>>>(x2, batch, fc1w, fc1b, fc2w, fc2b, out, NN);
}

// Round 8
// 277.979 us; speedup vs baseline: 1.1137x; 1.1137x over previous
//
#include <hip/hip_runtime.h>
#include <hip/hip_fp16.h>
#include <math.h>

#define NN 40000
#define EE 640000
#define NG 64
#define SCAN_BLOCKS ((NN + 1023) / 1024)

__device__ __forceinline__ float eluf(float x) { return x > 0.f ? x : expm1f(x); }

typedef const __attribute__((address_space(1))) char gas_char;
typedef __attribute__((address_space(3))) char las_char;

__device__ __forceinline__ void async_copy16(void* l, const void* g) {
  __builtin_amdgcn_global_load_lds((gas_char*)g, (las_char*)l, 16, 0, 0);
}

typedef __fp16 f16x2 __attribute__((ext_vector_type(2)));
__device__ __forceinline__ unsigned packh(float lo, float hi) {  // f32x2 -> packed fp16
  f16x2 p = __builtin_amdgcn_cvt_pkrtz(lo, hi);
  union { f16x2 h; unsigned u; } c; c.h = p; return c.u;
}
__device__ __forceinline__ float hlo(unsigned p) {
  union { unsigned u; f16x2 h; } c; c.u = p; return (float)c.h.x;
}
__device__ __forceinline__ float hhi(unsigned p) {
  union { unsigned u; f16x2 h; } c; c.u = p; return (float)c.h.y;
}

__global__ void zero_int_kernel(int* __restrict__ p, int n) {
  int i = blockIdx.x * 256 + threadIdx.x;
  if (i < n) p[i] = 0;
}

__global__ void count_deg_kernel(const int* __restrict__ dst, int* __restrict__ deg, int e) {
  int i = blockIdx.x * 256 + threadIdx.x;
  if (i < e) atomicAdd(&deg[dst[i]], 1);
}

__global__ __launch_bounds__(1024) void scanA_kernel(const int* __restrict__ deg,
                                                     int* __restrict__ row_ptr,
                                                     int* __restrict__ bsum, int n) {
  __shared__ int wsum[16];
  int t = threadIdx.x, lane = t & 63, wid = t >> 6;
  int i = blockIdx.x * 1024 + t;
  int v = (i < n) ? deg[i] : 0;
#pragma unroll
  for (int off = 1; off < 64; off <<= 1) {
    int u = __shfl_up(v, off);
    if (lane >= off) v += u;
  }
  if (lane == 63) wsum[wid] = v;
  __syncthreads();
  if (t < 16) {
    int w = wsum[t];
#pragma unroll
    for (int off = 1; off < 16; off <<= 1) {
      int u = __shfl_up(w, off);
      if (t >= off) w += u;
    }
    wsum[t] = w;
  }
  __syncthreads();
  if (wid > 0) v += wsum[wid - 1];
  if (i < n) row_ptr[i + 1] = v;
  if (t == 1023) bsum[blockIdx.x] = v;
}

__global__ void scanB_kernel(const int* __restrict__ bsum, int* __restrict__ boff, int nb) {
  int lane = threadIdx.x;
  int v = (lane < nb) ? bsum[lane] : 0;
  int orig = v;
#pragma unroll
  for (int off = 1; off < 64; off <<= 1) {
    int u = __shfl_up(v, off);
    if (lane >= off) v += u;
  }
  if (lane < nb) boff[lane] = v - orig;
}

__global__ __launch_bounds__(1024) void scanC_kernel(int* __restrict__ row_ptr,
                                                     const int* __restrict__ boff,
                                                     int* __restrict__ cursor, int n) {
  int i = blockIdx.x * 1024 + threadIdx.x;
  if (i < n) {
    int v = row_ptr[i + 1] + boff[i >> 10];
    row_ptr[i + 1] = v;
    if (i + 1 < n) cursor[i + 1] = v;
    if (i == 0) { cursor[0] = 0; row_ptr[0] = 0; }
  }
}

__global__ void scatter_kernel(const int* __restrict__ src, const int* __restrict__ dst,
                               int* __restrict__ cursor, int* __restrict__ csr_src, int e) {
  int i = blockIdx.x * 256 + threadIdx.x;
  if (i < e) {
    int d = dst[i];
    int pos = atomicAdd(&cursor[d], 1);
    csr_src[pos] = src[i];
  }
}

// GEMM (K=128, OUT=128): h = x @ W written as PACKED FP16 pairs
// hb[row*64 + j] = (fp16(h[row][j]), fp16(h[row][j+64])), plus fused als/ald.
__global__ __launch_bounds__(256, 2) void gemm128_kernel(
    const float* __restrict__ x, const float* __restrict__ W,
    const float* __restrict__ a_s, const float* __restrict__ a_d,
    unsigned* __restrict__ hb, float* __restrict__ als, float* __restrict__ ald)
{
  __shared__ float xs[64 * 128];
  __shared__ float ws[2][32 * 128];

  int t = threadIdx.x;
  int row0 = blockIdx.x * 64;

  {
    const char* xg = (const char*)(x + (size_t)row0 * 128);
    char* xl = (char*)xs;
#pragma unroll
    for (int it = 0; it < 8; ++it)
      async_copy16(xl + it * 4096 + t * 16, xg + it * 4096 + t * 16);
  }
  {
    const char* wg = (const char*)W;
    char* wl = (char*)ws[0];
#pragma unroll
    for (int p = 0; p < 4; ++p)
      async_copy16(wl + p * 4096 + t * 16, wg + p * 4096 + t * 16);
  }
  __syncthreads();

  int cg = t & 31, rg = t >> 5;
  int r0 = rg * 8;
  int jlo = 2 * cg;

  float acc[8][4];
#pragma unroll
  for (int r = 0; r < 8; ++r)
#pragma unroll
    for (int c = 0; c < 4; ++c) acc[r][c] = 0.f;

  for (int ch = 0; ch < 4; ++ch) {
    if (ch < 3) {
      const char* wg = (const char*)W + (size_t)(ch + 1) * 32 * 128 * 4;
      char* wl = (char*)ws[(ch + 1) & 1];
#pragma unroll
      for (int p = 0; p < 4; ++p)
        async_copy16(wl + p * 4096 + t * 16, wg + p * 4096 + t * 16);
    }
    const float* wc = ws[ch & 1];
    const float* xc = xs + ch * 32;
#pragma unroll
    for (int kk = 0; kk < 32; kk += 4) {
      float2 wlo[4], whi[4];
#pragma unroll
      for (int q = 0; q < 4; ++q) {
        wlo[q] = *reinterpret_cast<const float2*>(&wc[(kk + q) * 128 + jlo]);
        whi[q] = *reinterpret_cast<const float2*>(&wc[(kk + q) * 128 + 64 + jlo]);
      }
#pragma unroll
      for (int r = 0; r < 8; ++r) {
        float4 xv = *reinterpret_cast<const float4*>(&xc[(r0 + r) * 128 + kk]);
        float a0 = acc[r][0], a1 = acc[r][1], a2 = acc[r][2], a3 = acc[r][3];
        a0 = fmaf(xv.x, wlo[0].x, a0); a1 = fmaf(xv.x, wlo[0].y, a1);
        a2 = fmaf(xv.x, whi[0].x, a2); a3 = fmaf(xv.x, whi[0].y, a3);
        a0 = fmaf(xv.y, wlo[1].x, a0); a1 = fmaf(xv.y, wlo[1].y, a1);
        a2 = fmaf(xv.y, whi[1].x, a2); a3 = fmaf(xv.y, whi[1].y, a3);
        a0 = fmaf(xv.z, wlo[2].x, a0); a1 = fmaf(xv.z, wlo[2].y, a1);
        a2 = fmaf(xv.z, whi[2].x, a2); a3 = fmaf(xv.z, whi[2].y, a3);
        a0 = fmaf(xv.w, wlo[3].x, a0); a1 = fmaf(xv.w, wlo[3].y, a1);
        a2 = fmaf(xv.w, whi[3].x, a2); a3 = fmaf(xv.w, whi[3].y, a3);
        acc[r][0] = a0; acc[r][1] = a1; acc[r][2] = a2; acc[r][3] = a3;
      }
    }
    __syncthreads();
  }

#pragma unroll
  for (int r = 0; r < 8; ++r) {
    uint2 pv;
    pv.x = packh(acc[r][0], acc[r][2]);
    pv.y = packh(acc[r][1], acc[r][3]);
    *reinterpret_cast<uint2*>(&hb[(size_t)(row0 + r0 + r) * 64 + jlo]) = pv;
  }

  float as0 = a_s[jlo], as1 = a_s[jlo + 1], as2 = a_s[jlo + 64], as3 = a_s[jlo + 65];
  float ad0 = a_d[jlo], ad1 = a_d[jlo + 1], ad2 = a_d[jlo + 64], ad3 = a_d[jlo + 65];
  int lane = t & 63;
#pragma unroll
  for (int r = 0; r < 8; ++r) {
    float psa = fmaf(acc[r][0], as0, acc[r][1] * as1);
    float psb = fmaf(acc[r][2], as2, acc[r][3] * as3);
    float pda = fmaf(acc[r][0], ad0, acc[r][1] * ad1);
    float pdb = fmaf(acc[r][2], ad2, acc[r][3] * ad3);
#pragma unroll
    for (int m = 1; m < 16; m <<= 1) {
      psa += __shfl_xor(psa, m); psb += __shfl_xor(psb, m);
      pda += __shfl_xor(pda, m); pdb += __shfl_xor(pdb, m);
    }
    if ((lane & 15) == 0) {
      int hA = (lane >> 4) & 1;
      size_t row = (size_t)(row0 + r0 + r);
      als[row * 4 + hA] = psa; als[row * 4 + hA + 2] = psb;
      ald[row * 4 + hA] = pda; ald[row * 4 + hA + 2] = pdb;
    }
  }
}

// GEMM (K=128, OUT=32) f32 out, fused single-head als/ald.
__global__ __launch_bounds__(256, 2) void gemm32_kernel(
    const float* __restrict__ x, const float* __restrict__ W,
    const float* __restrict__ a_s, const float* __restrict__ a_d,
    float* __restrict__ h, float* __restrict__ als, float* __restrict__ ald)
{
  __shared__ float xs[64 * 128];
  __shared__ float ws[2][32 * 32];
  int t = threadIdx.x;
  int row0 = blockIdx.x * 64;
  {
    const char* xg = (const char*)(x + (size_t)row0 * 128);
    char* xl = (char*)xs;
#pragma unroll
    for (int it = 0; it < 8; ++it)
      async_copy16(xl + it * 4096 + t * 16, xg + it * 4096 + t * 16);
  }
  async_copy16((char*)ws[0] + t * 16, (const char*)W + t * 16);
  __syncthreads();

  int cg = t & 7, rg = t >> 3;
  int r0 = rg * 2, c0 = cg * 4;
  float acc[2][4];
#pragma unroll
  for (int r = 0; r < 2; ++r)
#pragma unroll
    for (int c = 0; c < 4; ++c) acc[r][c] = 0.f;

  for (int ch = 0; ch < 4; ++ch) {
    if (ch < 3) {
      const char* wg = (const char*)W + (size_t)(ch + 1) * 32 * 32 * 4;
      async_copy16((char*)ws[(ch + 1) & 1] + t * 16, wg + t * 16);
    }
    const float* wc = ws[ch & 1];
    const float* xc = xs + ch * 32;
#pragma unroll
    for (int kk = 0; kk < 32; kk += 4) {
      float4 wv[4];
#pragma unroll
      for (int q = 0; q < 4; ++q)
        wv[q] = *reinterpret_cast<const float4*>(&wc[(kk + q) * 32 + c0]);
#pragma unroll
      for (int r = 0; r < 2; ++r) {
        float4 xv = *reinterpret_cast<const float4*>(&xc[(r0 + r) * 128 + kk]);
#pragma unroll
        for (int c = 0; c < 4; ++c) {
          float a = acc[r][c];
          a = fmaf(xv.x, (&wv[0].x)[c], a);
          a = fmaf(xv.y, (&wv[1].x)[c], a);
          a = fmaf(xv.z, (&wv[2].x)[c], a);
          a = fmaf(xv.w, (&wv[3].x)[c], a);
          acc[r][c] = a;
        }
      }
    }
    __syncthreads();
  }

#pragma unroll
  for (int r = 0; r < 2; ++r) {
    float4 hv = make_float4(acc[r][0], acc[r][1], acc[r][2], acc[r][3]);
    *reinterpret_cast<float4*>(&h[(size_t)(row0 + r0 + r) * 32 + c0]) = hv;
  }
  float asv[4], adv[4];
#pragma unroll
  for (int c = 0; c < 4; ++c) { asv[c] = a_s[c0 + c]; adv[c] = a_d[c0 + c]; }
#pragma unroll
  for (int r = 0; r < 2; ++r) {
    float ps = acc[r][0] * asv[0] + acc[r][1] * asv[1] + acc[r][2] * asv[2] + acc[r][3] * asv[3];
    float pd = acc[r][0] * adv[0] + acc[r][1] * adv[1] + acc[r][2] * adv[2] + acc[r][3] * adv[3];
#pragma unroll
    for (int m = 1; m < 8; m <<= 1) { ps += __shfl_xor(ps, m); pd += __shfl_xor(pd, m); }
    if ((t & 7) == 0) {
      als[row0 + r0 + r] = ps;
      ald[row0 + r0 + r] = pd;
    }
  }
}

// Aggregate for OUT=128 (4 heads x 32), packed-fp16 h gather.
// One wave per dst node. No-max softmax (logits bounded, exp f32-safe).
// Half-wave edge split + unroll x2 (round-5 proven structure).
__global__ __launch_bounds__(256) void aggregate128_kernel(
    const unsigned* __restrict__ hb, const float* __restrict__ als, const float* __restrict__ ald,
    const int* __restrict__ row_ptr, const int* __restrict__ csr_src,
    const float* __restrict__ bias, const float* __restrict__ ln_g, const float* __restrict__ ln_b,
    float* __restrict__ out, int n)
{
  __shared__ int s_src[4][64];
  __shared__ float s_ex[4][64][4];
  int t = threadIdx.x, lane = t & 63, wid = t >> 6;
  int node = blockIdx.x * 4 + wid;
  if (node >= n) return;
  int start = row_ptr[node], end = row_ptr[node + 1];
  int deg = end - start;

  float4 adq = reinterpret_cast<const float4*>(ald)[node];
  float adl[4] = {adq.x, adq.y, adq.z, adq.w};
  int hi = lane >> 5, c = lane & 31;
  int h0 = c >> 4, h1 = h0 + 2;
  float a0 = 0.f, a1 = 0.f, a2 = 0.f, a3 = 0.f;   // features 2c,2c+1,2c+64,2c+65
  float ssum[4];

  if (deg <= 64) {
    // single-pass no-max softmax: one edge per lane
    bool valid = lane < deg;
    int s = 0;
    if (valid) s = csr_src[start + lane];
    float4 q = reinterpret_cast<const float4*>(als)[s];
    float v[4] = {q.x, q.y, q.z, q.w};
    float ex[4];
#pragma unroll
    for (int hh = 0; hh < 4; ++hh) {
      float w = v[hh] + adl[hh];
      w = w > 0.f ? w : 0.2f * w;
      ex[hh] = valid ? __expf(w) : 0.f;
      ssum[hh] = ex[hh];
    }
#pragma unroll
    for (int hh = 0; hh < 4; ++hh)
#pragma unroll
      for (int m = 1; m < 64; m <<= 1) ssum[hh] += __shfl_xor(ssum[hh], m);

    s_src[wid][lane] = s;
#pragma unroll
    for (int hh = 0; hh < 4; ++hh) s_ex[wid][lane][hh] = ex[hh];

    // half-wave split gather, unroll x2
    int d1 = deg >> 1, d0c = deg - d1;
    int base = hi ? d0c : 0;
    int cnt = hi ? d1 : d0c;
    float b0a = 0.f, b1a = 0.f, b2a = 0.f, b3a = 0.f;
    int j = 0;
    for (; j + 2 <= cnt; j += 2) {
      int sa = s_src[wid][base + j];
      int sb = s_src[wid][base + j + 1];
      uint2 ua = *reinterpret_cast<const uint2*>(&hb[(size_t)sa * 64 + 2 * c]);
      uint2 ub = *reinterpret_cast<const uint2*>(&hb[(size_t)sb * 64 + 2 * c]);
      float wa0 = s_ex[wid][base + j][h0], wa1 = s_ex[wid][base + j][h1];
      float wb0 = s_ex[wid][base + j + 1][h0], wb1 = s_ex[wid][base + j + 1][h1];
      a0 = fmaf(wa0, hlo(ua.x), a0); a1 = fmaf(wa0, hlo(ua.y), a1);
      a2 = fmaf(wa1, hhi(ua.x), a2); a3 = fmaf(wa1, hhi(ua.y), a3);
      b0a = fmaf(wb0, hlo(ub.x), b0a); b1a = fmaf(wb0, hlo(ub.y), b1a);
      b2a = fmaf(wb1, hhi(ub.x), b2a); b3a = fmaf(wb1, hhi(ub.y), b3a);
    }
    if (j < cnt) {
      int sa = s_src[wid][base + j];
      uint2 ua = *reinterpret_cast<const uint2*>(&hb[(size_t)sa * 64 + 2 * c]);
      float wa0 = s_ex[wid][base + j][h0], wa1 = s_ex[wid][base + j][h1];
      a0 = fmaf(wa0, hlo(ua.x), a0); a1 = fmaf(wa0, hlo(ua.y), a1);
      a2 = fmaf(wa1, hhi(ua.x), a2); a3 = fmaf(wa1, hhi(ua.y), a3);
    }
    a0 += b0a; a1 += b1a; a2 += b2a; a3 += b3a;
    // combine halves
    a0 += __shfl_xor(a0, 32); a1 += __shfl_xor(a1, 32);
    a2 += __shfl_xor(a2, 32); a3 += __shfl_xor(a3, 32);
  } else {
    // generic single-pass fallback (deg > 64: essentially never)
#pragma unroll
    for (int hh = 0; hh < 4; ++hh) ssum[hh] = 0.f;
    for (int eb = start; eb < end; eb += 64) {
      int e = eb + lane;
      int s = 0;
      float exv[4] = {0.f, 0.f, 0.f, 0.f};
      if (e < end) {
        s = csr_src[e];
        float4 q = reinterpret_cast<const float4*>(als)[s];
        float av[4] = {q.x, q.y, q.z, q.w};
#pragma unroll
        for (int hh = 0; hh < 4; ++hh) {
          float v = av[hh] + adl[hh];
          v = v > 0.f ? v : 0.2f * v;
          exv[hh] = __expf(v);
          ssum[hh] += exv[hh];
        }
      }
      s_src[wid][lane] = s;
#pragma unroll
      for (int hh = 0; hh < 4; ++hh) s_ex[wid][lane][hh] = exv[hh];
      int cnt = end - eb; if (cnt > 64) cnt = 64;
      for (int j = 0; j < cnt; ++j) {
        int sj = s_src[wid][j];
        uint2 u = *reinterpret_cast<const uint2*>(&hb[(size_t)sj * 64 + 2 * c]);
        float w0 = s_ex[wid][j][h0], w1 = s_ex[wid][j][h1];
        a0 = fmaf(w0, hlo(u.x), a0); a1 = fmaf(w0, hlo(u.y), a1);
        a2 = fmaf(w1, hhi(u.x), a2); a3 = fmaf(w1, hhi(u.y), a3);
      }
    }
#pragma unroll
    for (int hh = 0; hh < 4; ++hh)
#pragma unroll
      for (int m = 1; m < 64; m <<= 1) ssum[hh] += __shfl_xor(ssum[hh], m);
    // both halves computed all edges here -> halve
    a0 *= 0.5f; a1 *= 0.5f; a2 *= 0.5f; a3 *= 0.5f;
    a0 += __shfl_xor(a0, 32); a1 += __shfl_xor(a1, 32);
    a2 += __shfl_xor(a2, 32); a3 += __shfl_xor(a3, 32);
  }

  float2 blo = *reinterpret_cast<const float2*>(&bias[2 * c]);
  float2 bhi = *reinterpret_cast<const float2*>(&bias[2 * c + 64]);
  float is0 = 1.f / (ssum[h0] + 1e-16f), is1 = 1.f / (ssum[h1] + 1e-16f);
  float o0 = a0 * is0 + blo.x;
  float o1 = a1 * is0 + blo.y;
  float o2 = a2 * is1 + bhi.x;
  float o3 = a3 * is1 + bhi.y;
  // LN via E[x^2]-mu^2: two co-issued reduction chains
  float red = o0 + o1 + o2 + o3;
  float sq2 = o0 * o0 + o1 * o1 + o2 * o2 + o3 * o3;
#pragma unroll
  for (int m = 1; m < 64; m <<= 1) {
    red += __shfl_xor(red, m);
    sq2 += __shfl_xor(sq2, m);
  }
  float mu = red * (1.f / 256.f);       // each feature counted twice across halves
  float var = sq2 * (1.f / 256.f) - mu * mu;
  float rstd = rsqrtf(var + 1e-5f);
  int f = 2 * c + 64 * hi;
  float2 gv = *reinterpret_cast<const float2*>(&ln_g[f]);
  float2 bv = *reinterpret_cast<const float2*>(&ln_b[f]);
  float dx = (hi ? o2 : o0) - mu, dy = (hi ? o3 : o1) - mu;
  float2 yv;
  yv.x = eluf(dx * rstd * gv.x + bv.x);
  yv.y = eluf(dy * rstd * gv.y + bv.y);
  *reinterpret_cast<float2*>(&out[(size_t)node * 128 + f]) = yv;
}

// Aggregate for OUT=32 single head (f32 h rows). No-max softmax,
// half-wave edge split, unroll x2 (round-5 proven structure).
__global__ __launch_bounds__(256) void aggregate32_kernel(
    const float* __restrict__ h, const float* __restrict__ als, const float* __restrict__ ald,
    const int* __restrict__ row_ptr, const int* __restrict__ csr_src,
    const float* __restrict__ bias, const float* __restrict__ ln_g, const float* __restrict__ ln_b,
    float* __restrict__ out, int n)
{
  __shared__ int s_src[4][64];
  __shared__ float s_ex[4][64];
  int t = threadIdx.x, lane = t & 63, wid = t >> 6;
  int node = blockIdx.x * 4 + wid;
  if (node >= n) return;
  int start = row_ptr[node], end = row_ptr[node + 1];
  int deg = end - start;
  float adl = ald[node];
  int hi = lane >> 5, col = lane & 31;
  float acc0 = 0.f, ssum = 0.f;

  if (deg <= 64) {
    bool valid = lane < deg;
    int s = 0;
    if (valid) s = csr_src[start + lane];
    float v = als[s] + adl;
    v = v > 0.f ? v : 0.2f * v;
    float ex = valid ? __expf(v) : 0.f;
    ssum = ex;
#pragma unroll
    for (int m = 1; m < 64; m <<= 1) ssum += __shfl_xor(ssum, m);
    s_src[wid][lane] = s;
    s_ex[wid][lane] = ex;

    int d1 = deg >> 1, d0c = deg - d1;
    int base = hi ? d0c : 0;
    int cnt = hi ? d1 : d0c;
    float acc1 = 0.f;
    int j = 0;
    for (; j + 2 <= cnt; j += 2) {
      int sa = s_src[wid][base + j];
      int sb = s_src[wid][base + j + 1];
      float ha = h[(size_t)sa * 32 + col];
      float hbv = h[(size_t)sb * 32 + col];
      acc0 = fmaf(s_ex[wid][base + j], ha, acc0);
      acc1 = fmaf(s_ex[wid][base + j + 1], hbv, acc1);
    }
    if (j < cnt)
      acc0 = fmaf(s_ex[wid][base + j], h[(size_t)s_src[wid][base + j] * 32 + col], acc0);
    acc0 += acc1;
    acc0 += __shfl_xor(acc0, 32);
  } else {
    for (int eb = start; eb < end; eb += 64) {
      int e = eb + lane;
      int s = 0; float ex = 0.f;
      if (e < end) {
        s = csr_src[e];
        float v = als[s] + adl;
        v = v > 0.f ? v : 0.2f * v;
        ex = __expf(v);
        ssum += ex;
      }
      s_src[wid][lane] = s;
      s_ex[wid][lane] = ex;
      int cnt = end - eb; if (cnt > 64) cnt = 64;
      for (int j = 0; j < cnt; ++j)
        acc0 = fmaf(s_ex[wid][j], h[(size_t)s_src[wid][j] * 32 + col], acc0);
    }
#pragma unroll
    for (int m = 1; m < 64; m <<= 1) ssum += __shfl_xor(ssum, m);
    acc0 *= 0.5f;
    acc0 += __shfl_xor(acc0, 32);
  }

  float o0 = acc0 / (ssum + 1e-16f) + bias[col];
  float red = o0, sq2 = o0 * o0;
#pragma unroll
  for (int m = 1; m < 64; m <<= 1) {
    red += __shfl_xor(red, m);
    sq2 += __shfl_xor(sq2, m);
  }
  float mu = red * (1.f / 64.f);
  float var = sq2 * (1.f / 64.f) - mu * mu;
  float rstd = rsqrtf(var + 1e-5f);
  float y0 = (o0 - mu) * rstd * ln_g[col] + ln_b[col];
  if (lane < 32) out[(size_t)node * 32 + col] = eluf(y0);
}

__device__ __forceinline__ int lower_bound_dev(const int* a, int n, int key) {
  int lo = 0, hi = n;
  while (lo < hi) { int mid = (lo + hi) >> 1; if (a[mid] < key) lo = mid + 1; else hi = mid; }
  return lo;
}

// Fused global mean-pool + 2-layer classifier: one block per group.
__global__ __launch_bounds__(256) void poolfc_kernel(
    const float* __restrict__ x2, const int* __restrict__ batch,
    const float* __restrict__ fc1w, const float* __restrict__ fc1b,
    const float* __restrict__ fc2w, const float* __restrict__ fc2b,
    float* __restrict__ out, int n)
{
  int g = blockIdx.x;
  int lo = lower_bound_dev(batch, n, g);
  int hi = lower_bound_dev(batch, n, g + 1);
  int t = threadIdx.x;
  int c = t & 31, r = t >> 5;
  float acc = 0.f;
  for (int i = lo + r; i < hi; i += 8) acc += x2[(size_t)i * 32 + c];
  __shared__ float red[8][32];
  __shared__ float hgl[32];
  __shared__ float zl[16];
  red[r][c] = acc;
  __syncthreads();
  if (r == 0) {
    float s = 0.f;
#pragma unroll
    for (int k = 0; k < 8; ++k) s += red[k][c];
    float cnt = (float)(hi - lo);
    hgl[c] = s / fmaxf(cnt, 1.f);
  }
  __syncthreads();
  if (t < 16) {
    float a = fc1b[t];
#pragma unroll
    for (int k = 0; k < 32; ++k) a = fmaf(hgl[k], fc1w[k * 16 + t], a);
    zl[t] = fmaxf(a, 0.f);
  }
  __syncthreads();
  if (t < 2) {
    float a = fc2b[t];
#pragma unroll
    for (int j = 0; j < 16; ++j) a = fmaf(zl[j], fc2w[j * 2 + t], a);
    out[g * 2 + t] = a;
  }
}

extern "C" void kernel_launch(void* const* d_in, const int* in_sizes, int n_in,
                              void* d_out, int out_size, void* d_ws, size_t ws_size,
                              hipStream_t stream) {
  const float* x    = (const float*)d_in[0];
  const int*   ei   = (const int*)d_in[1];
  const int*   batch= (const int*)d_in[2];
  const float* W0   = (const float*)d_in[3];
  const float* as0  = (const float*)d_in[4];
  const float* ad0  = (const float*)d_in[5];
  const float* b0   = (const float*)d_in[6];
  const float* ln0g = (const float*)d_in[7];
  const float* ln0b = (const float*)d_in[8];
  const float* W1   = (const float*)d_in[9];
  const float* as1  = (const float*)d_in[10];
  const float* ad1  = (const float*)d_in[11];
  const float* b1   = (const float*)d_in[12];
  const float* ln1g = (const float*)d_in[13];
  const float* ln1b = (const float*)d_in[14];
  const float* W2   = (const float*)d_in[15];
  const float* as2  = (const float*)d_in[16];
  const float* ad2  = (const float*)d_in[17];
  const float* b2   = (const float*)d_in[18];
  const float* ln2g = (const float*)d_in[19];
  const float* ln2b = (const float*)d_in[20];
  const float* fc1w = (const float*)d_in[21];
  const float* fc1b = (const float*)d_in[22];
  const float* fc2w = (const float*)d_in[23];
  const float* fc2b = (const float*)d_in[24];
  float* out = (float*)d_out;

  const int* srce = ei;
  const int* dste = ei + EE;

  unsigned* hb = (unsigned*)d_ws;              // N*64 packed fp16 pairs
  float* B2  = (float*)(hb + (size_t)NN * 64); // N*128
  float* als = B2 + (size_t)NN * 128;          // N*4
  float* ald = als + (size_t)NN * 4;           // N*4
  float* h2  = ald + (size_t)NN * 4;           // N*32
  float* x2  = h2 + (size_t)NN * 32;           // N*32
  int* deg      = (int*)(x2 + (size_t)NN * 32);// N
  int* row_ptr  = deg + NN;                    // N+1
  int* cursor   = row_ptr + NN + 1;            // N
  int* csr_src  = cursor + NN;                 // E
  int* bsum     = csr_src + EE;                // SCAN_BLOCKS
  int* boff     = bsum + SCAN_BLOCKS;          // SCAN_BLOCKS

  // CSR build (shared by all 3 layers)
  zero_int_kernel<<<(NN + 255) / 256, 256, 0, stream>>>(deg, NN);
  count_deg_kernel<<<(EE + 255) / 256, 256, 0, stream>>>(dste, deg, EE);
  scanA_kernel<<<SCAN_BLOCKS, 1024, 0, stream>>>(deg, row_ptr, bsum, NN);
  scanB_kernel<<<1, 64, 0, stream>>>(bsum, boff, SCAN_BLOCKS);
  scanC_kernel<<<SCAN_BLOCKS, 1024, 0, stream>>>(row_ptr, boff, cursor, NN);
  scatter_kernel<<<(EE + 255) / 256, 256, 0, stream>>>(srce, dste, cursor, csr_src, EE);

  // layer 0
  gemm128_kernel<<<625, 256, 0, stream>>>(x, W0, as0, ad0, hb, als, ald);
  aggregate128_kernel<<<(NN + 3) / 4, 256, 0, stream>>>(hb, als, ald, row_ptr, csr_src,
                                                        b0, ln0g, ln0b, B2, NN);
  // layer 1
  gemm128_kernel<<<625, 256, 0, stream>>>(B2, W1, as1, ad1, hb, als, ald);
  aggregate128_kernel<<<(NN + 3) / 4, 256, 0, stream>>>(hb, als, ald, row_ptr, csr_src,
                                                        b1, ln1g, ln1b, B2, NN);
  // layer 2
  gemm32_kernel<<<625, 256, 0, stream>>>(B2, W2, as2, ad2, h2, als, ald);
  aggregate32_kernel<<<(NN + 3) / 4, 256, 0, stream>>>(h2, als, ald, row_ptr, csr_src,
                                                       b2, ln2g, ln2b, x2, NN);
  // pool + classifier (fused)
  poolfc_kernel<<<NG, 256, 0, stream>>>(x2, batch, fc1w, fc1b, fc2w, fc2b, out, NN);
}

// Round 9
// 270.025 us; speedup vs baseline: 1.1465x; 1.0295x over previous
//
#include <hip/hip_runtime.h>
#include <hip/hip_fp16.h>
#include <math.h>

#define NN 40000
#define EE 640000
#define NG 64
#define SCAN_BLOCKS ((NN + 1023) / 1024)

__device__ __forceinline__ float eluf(float x) { return x > 0.f ? x : expm1f(x); }

typedef const __attribute__((address_space(1))) char gas_char;
typedef __attribute__((address_space(3))) char las_char;

__device__ __forceinline__ void async_copy16(void* l, const void* g) {
  __builtin_amdgcn_global_load_lds((gas_char*)g, (las_char*)l, 16, 0, 0);
}

typedef __fp16 f16x2 __attribute__((ext_vector_type(2)));
__device__ __forceinline__ unsigned packh(float lo, float hi) {  // f32x2 -> packed fp16
  f16x2 p = __builtin_amdgcn_cvt_pkrtz(lo, hi);
  union { f16x2 h; unsigned u; } c; c.h = p; return c.u;
}
__device__ __forceinline__ float hlo(unsigned p) {
  union { unsigned u; f16x2 h; } c; c.u = p; return (float)c.h.x;
}
__device__ __forceinline__ float hhi(unsigned p) {
  union { unsigned u; f16x2 h; } c; c.u = p; return (float)c.h.y;
}

__global__ void zero_int_kernel(int* __restrict__ p, int n) {
  int i = blockIdx.x * 256 + threadIdx.x;
  if (i < n) p[i] = 0;
}

__global__ void count_deg_kernel(const int* __restrict__ dst, int* __restrict__ deg, int e) {
  int i = blockIdx.x * 256 + threadIdx.x;
  if (i < e) atomicAdd(&deg[dst[i]], 1);
}

__global__ __launch_bounds__(1024) void scanA_kernel(const int* __restrict__ deg,
                                                     int* __restrict__ row_ptr,
                                                     int* __restrict__ bsum, int n) {
  __shared__ int wsum[16];
  int t = threadIdx.x, lane = t & 63, wid = t >> 6;
  int i = blockIdx.x * 1024 + t;
  int v = (i < n) ? deg[i] : 0;
#pragma unroll
  for (int off = 1; off < 64; off <<= 1) {
    int u = __shfl_up(v, off);
    if (lane >= off) v += u;
  }
  if (lane == 63) wsum[wid] = v;
  __syncthreads();
  if (t < 16) {
    int w = wsum[t];
#pragma unroll
    for (int off = 1; off < 16; off <<= 1) {
      int u = __shfl_up(w, off);
      if (t >= off) w += u;
    }
    wsum[t] = w;
  }
  __syncthreads();
  if (wid > 0) v += wsum[wid - 1];
  if (i < n) row_ptr[i + 1] = v;
  if (t == 1023) bsum[blockIdx.x] = v;
}

__global__ void scanB_kernel(const int* __restrict__ bsum, int* __restrict__ boff, int nb) {
  int lane = threadIdx.x;
  int v = (lane < nb) ? bsum[lane] : 0;
  int orig = v;
#pragma unroll
  for (int off = 1; off < 64; off <<= 1) {
    int u = __shfl_up(v, off);
    if (lane >= off) v += u;
  }
  if (lane < nb) boff[lane] = v - orig;
}

__global__ __launch_bounds__(1024) void scanC_kernel(int* __restrict__ row_ptr,
                                                     const int* __restrict__ boff,
                                                     int* __restrict__ cursor, int n) {
  int i = blockIdx.x * 1024 + threadIdx.x;
  if (i < n) {
    int v = row_ptr[i + 1] + boff[i >> 10];
    row_ptr[i + 1] = v;
    if (i + 1 < n) cursor[i + 1] = v;
    if (i == 0) { cursor[0] = 0; row_ptr[0] = 0; }
  }
}

__global__ void scatter_kernel(const int* __restrict__ src, const int* __restrict__ dst,
                               int* __restrict__ cursor, int* __restrict__ csr_src, int e) {
  int i = blockIdx.x * 256 + threadIdx.x;
  if (i < e) {
    int d = dst[i];
    int pos = atomicAdd(&cursor[d], 1);
    csr_src[pos] = src[i];
  }
}

// GEMM (K=128, OUT=128): h = x @ W written as PACKED FP16 pairs.
// LDS 48KB (x k-chunked dbuf 16KB + W dbuf 32KB) -> 3 blocks/CU.
__global__ __launch_bounds__(256, 3) void gemm128_kernel(
    const float* __restrict__ x, const float* __restrict__ W,
    const float* __restrict__ a_s, const float* __restrict__ a_d,
    unsigned* __restrict__ hb, float* __restrict__ als, float* __restrict__ ald)
{
  __shared__ float xs[2][64 * 32];
  __shared__ float ws[2][32 * 128];

  int t = threadIdx.x;
  int row0 = blockIdx.x * 64;
  const char* xgb = (const char*)x + (size_t)row0 * 512;

  // stage chunk 0 (x k-chunk + W chunk)
  {
    int li0 = t, li1 = t + 256;
    async_copy16((char*)xs[0] + li0 * 16, xgb + (li0 >> 3) * 512 + (li0 & 7) * 16);
    async_copy16((char*)xs[0] + li1 * 16, xgb + (li1 >> 3) * 512 + (li1 & 7) * 16);
    const char* wg = (const char*)W;
#pragma unroll
    for (int p = 0; p < 4; ++p)
      async_copy16((char*)ws[0] + p * 4096 + t * 16, wg + p * 4096 + t * 16);
  }
  __syncthreads();

  int cg = t & 31, rg = t >> 5;
  int r0 = rg * 8;
  int jlo = 2 * cg;

  float acc[8][4];
#pragma unroll
  for (int r = 0; r < 8; ++r)
#pragma unroll
    for (int c = 0; c < 4; ++c) acc[r][c] = 0.f;

  for (int ch = 0; ch < 4; ++ch) {
    if (ch < 3) {
      int b = (ch + 1) & 1;
      int li0 = t, li1 = t + 256;
      const char* xg = xgb + (ch + 1) * 128;
      async_copy16((char*)xs[b] + li0 * 16, xg + (li0 >> 3) * 512 + (li0 & 7) * 16);
      async_copy16((char*)xs[b] + li1 * 16, xg + (li1 >> 3) * 512 + (li1 & 7) * 16);
      const char* wg = (const char*)W + (size_t)(ch + 1) * 32 * 128 * 4;
#pragma unroll
      for (int p = 0; p < 4; ++p)
        async_copy16((char*)ws[b] + p * 4096 + t * 16, wg + p * 4096 + t * 16);
    }
    const float* wc = ws[ch & 1];
    const float* xc = xs[ch & 1];
#pragma unroll
    for (int kk = 0; kk < 32; kk += 4) {
      float2 wlo[4], whi[4];
#pragma unroll
      for (int q = 0; q < 4; ++q) {
        wlo[q] = *reinterpret_cast<const float2*>(&wc[(kk + q) * 128 + jlo]);
        whi[q] = *reinterpret_cast<const float2*>(&wc[(kk + q) * 128 + 64 + jlo]);
      }
#pragma unroll
      for (int r = 0; r < 8; ++r) {
        float4 xv = *reinterpret_cast<const float4*>(&xc[(r0 + r) * 32 + kk]);
        float a0 = acc[r][0], a1 = acc[r][1], a2 = acc[r][2], a3 = acc[r][3];
        a0 = fmaf(xv.x, wlo[0].x, a0); a1 = fmaf(xv.x, wlo[0].y, a1);
        a2 = fmaf(xv.x, whi[0].x, a2); a3 = fmaf(xv.x, whi[0].y, a3);
        a0 = fmaf(xv.y, wlo[1].x, a0); a1 = fmaf(xv.y, wlo[1].y, a1);
        a2 = fmaf(xv.y, whi[1].x, a2); a3 = fmaf(xv.y, whi[1].y, a3);
        a0 = fmaf(xv.z, wlo[2].x, a0); a1 = fmaf(xv.z, wlo[2].y, a1);
        a2 = fmaf(xv.z, whi[2].x, a2); a3 = fmaf(xv.z, whi[2].y, a3);
        a0 = fmaf(xv.w, wlo[3].x, a0); a1 = fmaf(xv.w, wlo[3].y, a1);
        a2 = fmaf(xv.w, whi[3].x, a2); a3 = fmaf(xv.w, whi[3].y, a3);
        acc[r][0] = a0; acc[r][1] = a1; acc[r][2] = a2; acc[r][3] = a3;
      }
    }
    __syncthreads();
  }

#pragma unroll
  for (int r = 0; r < 8; ++r) {
    uint2 pv;
    pv.x = packh(acc[r][0], acc[r][2]);
    pv.y = packh(acc[r][1], acc[r][3]);
    *reinterpret_cast<uint2*>(&hb[(size_t)(row0 + r0 + r) * 64 + jlo]) = pv;
  }

  float as0 = a_s[jlo], as1 = a_s[jlo + 1], as2 = a_s[jlo + 64], as3 = a_s[jlo + 65];
  float ad0 = a_d[jlo], ad1 = a_d[jlo + 1], ad2 = a_d[jlo + 64], ad3 = a_d[jlo + 65];
  int lane = t & 63;
#pragma unroll
  for (int r = 0; r < 8; ++r) {
    float psa = fmaf(acc[r][0], as0, acc[r][1] * as1);
    float psb = fmaf(acc[r][2], as2, acc[r][3] * as3);
    float pda = fmaf(acc[r][0], ad0, acc[r][1] * ad1);
    float pdb = fmaf(acc[r][2], ad2, acc[r][3] * ad3);
#pragma unroll
    for (int m = 1; m < 16; m <<= 1) {
      psa += __shfl_xor(psa, m); psb += __shfl_xor(psb, m);
      pda += __shfl_xor(pda, m); pdb += __shfl_xor(pdb, m);
    }
    if ((lane & 15) == 0) {
      int hA = (lane >> 4) & 1;
      size_t row = (size_t)(row0 + r0 + r);
      als[row * 4 + hA] = psa; als[row * 4 + hA + 2] = psb;
      ald[row * 4 + hA] = pda; ald[row * 4 + hA + 2] = pdb;
    }
  }
}

// GEMM (K=128, OUT=32) f32 out, fused single-head als/ald.
__global__ __launch_bounds__(256, 2) void gemm32_kernel(
    const float* __restrict__ x, const float* __restrict__ W,
    const float* __restrict__ a_s, const float* __restrict__ a_d,
    float* __restrict__ h, float* __restrict__ als, float* __restrict__ ald)
{
  __shared__ float xs[64 * 128];
  __shared__ float ws[2][32 * 32];
  int t = threadIdx.x;
  int row0 = blockIdx.x * 64;
  {
    const char* xg = (const char*)(x + (size_t)row0 * 128);
    char* xl = (char*)xs;
#pragma unroll
    for (int it = 0; it < 8; ++it)
      async_copy16(xl + it * 4096 + t * 16, xg + it * 4096 + t * 16);
  }
  async_copy16((char*)ws[0] + t * 16, (const char*)W + t * 16);
  __syncthreads();

  int cg = t & 7, rg = t >> 3;
  int r0 = rg * 2, c0 = cg * 4;
  float acc[2][4];
#pragma unroll
  for (int r = 0; r < 2; ++r)
#pragma unroll
    for (int c = 0; c < 4; ++c) acc[r][c] = 0.f;

  for (int ch = 0; ch < 4; ++ch) {
    if (ch < 3) {
      const char* wg = (const char*)W + (size_t)(ch + 1) * 32 * 32 * 4;
      async_copy16((char*)ws[(ch + 1) & 1] + t * 16, wg + t * 16);
    }
    const float* wc = ws[ch & 1];
    const float* xc = xs + ch * 32;
#pragma unroll
    for (int kk = 0; kk < 32; kk += 4) {
      float4 wv[4];
#pragma unroll
      for (int q = 0; q < 4; ++q)
        wv[q] = *reinterpret_cast<const float4*>(&wc[(kk + q) * 32 + c0]);
#pragma unroll
      for (int r = 0; r < 2; ++r) {
        float4 xv = *reinterpret_cast<const float4*>(&xc[(r0 + r) * 128 + kk]);
#pragma unroll
        for (int c = 0; c < 4; ++c) {
          float a = acc[r][c];
          a = fmaf(xv.x, (&wv[0].x)[c], a);
          a = fmaf(xv.y, (&wv[1].x)[c], a);
          a = fmaf(xv.z, (&wv[2].x)[c], a);
          a = fmaf(xv.w, (&wv[3].x)[c], a);
          acc[r][c] = a;
        }
      }
    }
    __syncthreads();
  }

#pragma unroll
  for (int r = 0; r < 2; ++r) {
    float4 hv = make_float4(acc[r][0], acc[r][1], acc[r][2], acc[r][3]);
    *reinterpret_cast<float4*>(&h[(size_t)(row0 + r0 + r) * 32 + c0]) = hv;
  }
  float asv[4], adv[4];
#pragma unroll
  for (int c = 0; c < 4; ++c) { asv[c] = a_s[c0 + c]; adv[c] = a_d[c0 + c]; }
#pragma unroll
  for (int r = 0; r < 2; ++r) {
    float ps = acc[r][0] * asv[0] + acc[r][1] * asv[1] + acc[r][2] * asv[2] + acc[r][3] * asv[3];
    float pd = acc[r][0] * adv[0] + acc[r][1] * adv[1] + acc[r][2] * adv[2] + acc[r][3] * adv[3];
#pragma unroll
    for (int m = 1; m < 8; m <<= 1) { ps += __shfl_xor(ps, m); pd += __shfl_xor(pd, m); }
    if ((t & 7) == 0) {
      als[row0 + r0 + r] = ps;
      ald[row0 + r0 + r] = pd;
    }
  }
}

// Aggregate for OUT=128 (4 heads x 32), packed-fp16 h gather.
// One wave per dst node, no-max softmax, half-wave edge split, unroll x2.
// ssum accumulated IN the gather loop (weights already loaded) -> no separate
// 4-head shfl reduction. Weights in LDS as float2 pairs {ex[h], ex[h+2]}.
__global__ __launch_bounds__(256) void aggregate128_kernel(
    const unsigned* __restrict__ hb, const float* __restrict__ als, const float* __restrict__ ald,
    const int* __restrict__ row_ptr, const int* __restrict__ csr_src,
    const float* __restrict__ bias, const float* __restrict__ ln_g, const float* __restrict__ ln_b,
    float* __restrict__ out, int n)
{
  __shared__ int s_src[4][64];
  __shared__ float2 s_w[4][64][2];
  int t = threadIdx.x, lane = t & 63, wid = t >> 6;
  int node = blockIdx.x * 4 + wid;
  if (node >= n) return;
  int start = row_ptr[node], end = row_ptr[node + 1];
  int deg = end - start;

  float4 adq = reinterpret_cast<const float4*>(ald)[node];
  float adl[4] = {adq.x, adq.y, adq.z, adq.w};
  int hi = lane >> 5, c = lane & 31;
  int hsel = c >> 4;                 // this lane's head pair: (hsel, hsel+2)
  float a0 = 0.f, a1 = 0.f, a2 = 0.f, a3 = 0.f;   // features 2c,2c+1,2c+64,2c+65
  float ssum0 = 0.f, ssum1 = 0.f;

  if (deg <= 64) {
    int s = 0;
    if (lane < deg) s = csr_src[start + lane];
    float4 q = reinterpret_cast<const float4*>(als)[s];
    float v[4] = {q.x, q.y, q.z, q.w};
    float ex[4];
#pragma unroll
    for (int hh = 0; hh < 4; ++hh) {
      float w = v[hh] + adl[hh];
      w = w > 0.f ? w : 0.2f * w;
      ex[hh] = __expf(w);
    }
    s_src[wid][lane] = s;
    s_w[wid][lane][0] = make_float2(ex[0], ex[2]);
    s_w[wid][lane][1] = make_float2(ex[1], ex[3]);

    // half-wave split gather, unroll x2, in-loop ssum
    int d1 = deg >> 1, d0c = deg - d1;
    int base = hi ? d0c : 0;
    int cnt = hi ? d1 : d0c;
    float b0a = 0.f, b1a = 0.f, b2a = 0.f, b3a = 0.f;
    float sb0 = 0.f, sb1 = 0.f;
    int j = 0;
    for (; j + 2 <= cnt; j += 2) {
      int sa = s_src[wid][base + j];
      int sb = s_src[wid][base + j + 1];
      uint2 ua = *reinterpret_cast<const uint2*>(&hb[(size_t)sa * 64 + 2 * c]);
      uint2 ub = *reinterpret_cast<const uint2*>(&hb[(size_t)sb * 64 + 2 * c]);
      float2 wa = s_w[wid][base + j][hsel];
      float2 wb = s_w[wid][base + j + 1][hsel];
      a0 = fmaf(wa.x, hlo(ua.x), a0); a1 = fmaf(wa.x, hlo(ua.y), a1);
      a2 = fmaf(wa.y, hhi(ua.x), a2); a3 = fmaf(wa.y, hhi(ua.y), a3);
      ssum0 += wa.x; ssum1 += wa.y;
      b0a = fmaf(wb.x, hlo(ub.x), b0a); b1a = fmaf(wb.x, hlo(ub.y), b1a);
      b2a = fmaf(wb.y, hhi(ub.x), b2a); b3a = fmaf(wb.y, hhi(ub.y), b3a);
      sb0 += wb.x; sb1 += wb.y;
    }
    if (j < cnt) {
      int sa = s_src[wid][base + j];
      uint2 ua = *reinterpret_cast<const uint2*>(&hb[(size_t)sa * 64 + 2 * c]);
      float2 wa = s_w[wid][base + j][hsel];
      a0 = fmaf(wa.x, hlo(ua.x), a0); a1 = fmaf(wa.x, hlo(ua.y), a1);
      a2 = fmaf(wa.y, hhi(ua.x), a2); a3 = fmaf(wa.y, hhi(ua.y), a3);
      ssum0 += wa.x; ssum1 += wa.y;
    }
    a0 += b0a; a1 += b1a; a2 += b2a; a3 += b3a;
    ssum0 += sb0; ssum1 += sb1;
    // combine halves
    a0 += __shfl_xor(a0, 32); a1 += __shfl_xor(a1, 32);
    a2 += __shfl_xor(a2, 32); a3 += __shfl_xor(a3, 32);
    ssum0 += __shfl_xor(ssum0, 32); ssum1 += __shfl_xor(ssum1, 32);
  } else {
    // generic single-pass fallback (deg > 64: essentially never)
    for (int eb = start; eb < end; eb += 64) {
      int e = eb + lane;
      int s = 0;
      float exv[4] = {0.f, 0.f, 0.f, 0.f};
      if (e < end) {
        s = csr_src[e];
        float4 q = reinterpret_cast<const float4*>(als)[s];
        float av[4] = {q.x, q.y, q.z, q.w};
#pragma unroll
        for (int hh = 0; hh < 4; ++hh) {
          float v = av[hh] + adl[hh];
          v = v > 0.f ? v : 0.2f * v;
          exv[hh] = __expf(v);
        }
      }
      s_src[wid][lane] = s;
      s_w[wid][lane][0] = make_float2(exv[0], exv[2]);
      s_w[wid][lane][1] = make_float2(exv[1], exv[3]);
      int cnt = end - eb; if (cnt > 64) cnt = 64;
      for (int j = 0; j < cnt; ++j) {
        int sj = s_src[wid][j];
        uint2 u = *reinterpret_cast<const uint2*>(&hb[(size_t)sj * 64 + 2 * c]);
        float2 w = s_w[wid][j][hsel];
        a0 = fmaf(w.x, hlo(u.x), a0); a1 = fmaf(w.x, hlo(u.y), a1);
        a2 = fmaf(w.y, hhi(u.x), a2); a3 = fmaf(w.y, hhi(u.y), a3);
        ssum0 += w.x; ssum1 += w.y;
      }
    }
    // both halves computed all edges -> halve
    a0 *= 0.5f; a1 *= 0.5f; a2 *= 0.5f; a3 *= 0.5f;
    ssum0 *= 0.5f; ssum1 *= 0.5f;
    a0 += __shfl_xor(a0, 32); a1 += __shfl_xor(a1, 32);
    a2 += __shfl_xor(a2, 32); a3 += __shfl_xor(a3, 32);
    ssum0 += __shfl_xor(ssum0, 32); ssum1 += __shfl_xor(ssum1, 32);
  }

  float2 blo = *reinterpret_cast<const float2*>(&bias[2 * c]);
  float2 bhi = *reinterpret_cast<const float2*>(&bias[2 * c + 64]);
  float is0 = 1.f / (ssum0 + 1e-16f), is1 = 1.f / (ssum1 + 1e-16f);
  float o0 = a0 * is0 + blo.x;
  float o1 = a1 * is0 + blo.y;
  float o2 = a2 * is1 + bhi.x;
  float o3 = a3 * is1 + bhi.y;
  // LN via E[x^2]-mu^2: two co-issued reduction chains
  float red = o0 + o1 + o2 + o3;
  float sq2 = o0 * o0 + o1 * o1 + o2 * o2 + o3 * o3;
#pragma unroll
  for (int m = 1; m < 64; m <<= 1) {
    red += __shfl_xor(red, m);
    sq2 += __shfl_xor(sq2, m);
  }
  float mu = red * (1.f / 256.f);       // each feature counted twice across halves
  float var = sq2 * (1.f / 256.f) - mu * mu;
  float rstd = rsqrtf(var + 1e-5f);
  int f = 2 * c + 64 * hi;
  float2 gv = *reinterpret_cast<const float2*>(&ln_g[f]);
  float2 bv = *reinterpret_cast<const float2*>(&ln_b[f]);
  float dx = (hi ? o2 : o0) - mu, dy = (hi ? o3 : o1) - mu;
  float2 yv;
  yv.x = eluf(dx * rstd * gv.x + bv.x);
  yv.y = eluf(dy * rstd * gv.y + bv.y);
  *reinterpret_cast<float2*>(&out[(size_t)node * 128 + f]) = yv;
}

// Aggregate for OUT=32 single head (f32 h rows). No-max softmax,
// half-wave edge split, unroll x2, in-loop ssum.
__global__ __launch_bounds__(256) void aggregate32_kernel(
    const float* __restrict__ h, const float* __restrict__ als, const float* __restrict__ ald,
    const int* __restrict__ row_ptr, const int* __restrict__ csr_src,
    const float* __restrict__ bias, const float* __restrict__ ln_g, const float* __restrict__ ln_b,
    float* __restrict__ out, int n)
{
  __shared__ int s_src[4][64];
  __shared__ float s_ex[4][64];
  int t = threadIdx.x, lane = t & 63, wid = t >> 6;
  int node = blockIdx.x * 4 + wid;
  if (node >= n) return;
  int start = row_ptr[node], end = row_ptr[node + 1];
  int deg = end - start;
  float adl = ald[node];
  int hi = lane >> 5, col = lane & 31;
  float acc0 = 0.f, ssum = 0.f;

  if (deg <= 64) {
    int s = 0;
    if (lane < deg) s = csr_src[start + lane];
    float v = als[s] + adl;
    v = v > 0.f ? v : 0.2f * v;
    float ex = __expf(v);
    s_src[wid][lane] = s;
    s_ex[wid][lane] = ex;

    int d1 = deg >> 1, d0c = deg - d1;
    int base = hi ? d0c : 0;
    int cnt = hi ? d1 : d0c;
    float acc1 = 0.f, ssum1 = 0.f;
    int j = 0;
    for (; j + 2 <= cnt; j += 2) {
      int sa = s_src[wid][base + j];
      int sb = s_src[wid][base + j + 1];
      float ha = h[(size_t)sa * 32 + col];
      float hbv = h[(size_t)sb * 32 + col];
      float wa = s_ex[wid][base + j];
      float wb = s_ex[wid][base + j + 1];
      acc0 = fmaf(wa, ha, acc0); ssum += wa;
      acc1 = fmaf(wb, hbv, acc1); ssum1 += wb;
    }
    if (j < cnt) {
      float wa = s_ex[wid][base + j];
      acc0 = fmaf(wa, h[(size_t)s_src[wid][base + j] * 32 + col], acc0);
      ssum += wa;
    }
    acc0 += acc1; ssum += ssum1;
    acc0 += __shfl_xor(acc0, 32);
    ssum += __shfl_xor(ssum, 32);
  } else {
    for (int eb = start; eb < end; eb += 64) {
      int e = eb + lane;
      int s = 0; float ex = 0.f;
      if (e < end) {
        s = csr_src[e];
        float v = als[s] + adl;
        v = v > 0.f ? v : 0.2f * v;
        ex = __expf(v);
      }
      s_src[wid][lane] = s;
      s_ex[wid][lane] = ex;
      int cnt = end - eb; if (cnt > 64) cnt = 64;
      for (int j = 0; j < cnt; ++j) {
        float w = s_ex[wid][j];
        acc0 = fmaf(w, h[(size_t)s_src[wid][j] * 32 + col], acc0);
        ssum += w;
      }
    }
    acc0 *= 0.5f; ssum *= 0.5f;
    acc0 += __shfl_xor(acc0, 32);
    ssum += __shfl_xor(ssum, 32);
  }

  float o0 = acc0 / (ssum + 1e-16f) + bias[col];
  float red = o0, sq2 = o0 * o0;
#pragma unroll
  for (int m = 1; m < 64; m <<= 1) {
    red += __shfl_xor(red, m);
    sq2 += __shfl_xor(sq2, m);
  }
  float mu = red * (1.f / 64.f);
  float var = sq2 * (1.f / 64.f) - mu * mu;
  float rstd = rsqrtf(var + 1e-5f);
  float y0 = (o0 - mu) * rstd * ln_g[col] + ln_b[col];
  if (lane < 32) out[(size_t)node * 32 + col] = eluf(y0);
}

__device__ __forceinline__ int lower_bound_dev(const int* a, int n, int key) {
  int lo = 0, hi = n;
  while (lo < hi) { int mid = (lo + hi) >> 1; if (a[mid] < key) lo = mid + 1; else hi = mid; }
  return lo;
}

// Fused global mean-pool + 2-layer classifier: one block per group.
__global__ __launch_bounds__(256) void poolfc_kernel(
    const float* __restrict__ x2, const int* __restrict__ batch,
    const float* __restrict__ fc1w, const float* __restrict__ fc1b,
    const float* __restrict__ fc2w, const float* __restrict__ fc2b,
    float* __restrict__ out, int n)
{
  int g = blockIdx.x;
  int lo = lower_bound_dev(batch, n, g);
  int hi = lower_bound_dev(batch, n, g + 1);
  int t = threadIdx.x;
  int c = t & 31, r = t >> 5;
  float acc = 0.f;
  for (int i = lo + r; i < hi; i += 8) acc += x2[(size_t)i * 32 + c];
  __shared__ float red[8][32];
  __shared__ float hgl[32];
  __shared__ float zl[16];
  red[r][c] = acc;
  __syncthreads();
  if (r == 0) {
    float s = 0.f;
#pragma unroll
    for (int k = 0; k < 8; ++k) s += red[k][c];
    float cnt = (float)(hi - lo);
    hgl[c] = s / fmaxf(cnt, 1.f);
  }
  __syncthreads();
  if (t < 16) {
    float a = fc1b[t];
#pragma unroll
    for (int k = 0; k < 32; ++k) a = fmaf(hgl[k], fc1w[k * 16 + t], a);
    zl[t] = fmaxf(a, 0.f);
  }
  __syncthreads();
  if (t < 2) {
    float a = fc2b[t];
#pragma unroll
    for (int j = 0; j < 16; ++j) a = fmaf(zl[j], fc2w[j * 2 + t], a);
    out[g * 2 + t] = a;
  }
}

extern "C" void kernel_launch(void* const* d_in, const int* in_sizes, int n_in,
                              void* d_out, int out_size, void* d_ws, size_t ws_size,
                              hipStream_t stream) {
  const float* x    = (const float*)d_in[0];
  const int*   ei   = (const int*)d_in[1];
  const int*   batch= (const int*)d_in[2];
  const float* W0   = (const float*)d_in[3];
  const float* as0  = (const float*)d_in[4];
  const float* ad0  = (const float*)d_in[5];
  const float* b0   = (const float*)d_in[6];
  const float* ln0g = (const float*)d_in[7];
  const float* ln0b = (const float*)d_in[8];
  const float* W1   = (const float*)d_in[9];
  const float* as1  = (const float*)d_in[10];
  const float* ad1  = (const float*)d_in[11];
  const float* b1   = (const float*)d_in[12];
  const float* ln1g = (const float*)d_in[13];
  const float* ln1b = (const float*)d_in[14];
  const float* W2   = (const float*)d_in[15];
  const float* as2  = (const float*)d_in[16];
  const float* ad2  = (const float*)d_in[17];
  const float* b2   = (const float*)d_in[18];
  const float* ln2g = (const float*)d_in[19];
  const float* ln2b = (const float*)d_in[20];
  const float* fc1w = (const float*)d_in[21];
  const float* fc1b = (const float*)d_in[22];
  const float* fc2w = (const float*)d_in[23];
  const float* fc2b = (const float*)d_in[24];
  float* out = (float*)d_out;

  const int* srce = ei;
  const int* dste = ei + EE;

  unsigned* hb = (unsigned*)d_ws;              // N*64 packed fp16 pairs
  float* B2  = (float*)(hb + (size_t)NN * 64); // N*128
  float* als = B2 + (size_t)NN * 128;          // N*4
  float* ald = als + (size_t)NN * 4;           // N*4
  float* h2  = ald + (size_t)NN * 4;           // N*32
  float* x2  = h2 + (size_t)NN * 32;           // N*32
  int* deg      = (int*)(x2 + (size_t)NN * 32);// N
  int* row_ptr  = deg + NN;                    // N+1
  int* cursor   = row_ptr + NN + 1;            // N
  int* csr_src  = cursor + NN;                 // E
  int* bsum     = csr_src + EE;                // SCAN_BLOCKS
  int* boff     = bsum + SCAN_BLOCKS;          // SCAN_BLOCKS

  // CSR build (shared by all 3 layers)
  zero_int_kernel<<<(NN + 255) / 256, 256, 0, stream>>>(deg, NN);
  count_deg_kernel<<<(EE + 255) / 256, 256, 0, stream>>>(dste, deg, EE);
  scanA_kernel<<<SCAN_BLOCKS, 1024, 0, stream>>>(deg, row_ptr, bsum, NN);
  scanB_kernel<<<1, 64, 0, stream>>>(bsum, boff, SCAN_BLOCKS);
  scanC_kernel<<<SCAN_BLOCKS, 1024, 0, stream>>>(row_ptr, boff, cursor, NN);
  scatter_kernel<<<(EE + 255) / 256, 256, 0, stream>>>(srce, dste, cursor, csr_src, EE);

  // layer 0
  gemm128_kernel<<<625, 256, 0, stream>>>(x, W0, as0, ad0, hb, als, ald);
  aggregate128_kernel<<<(NN + 3) / 4, 256, 0, stream>>>(hb, als, ald, row_ptr, csr_src,
                                                        b0, ln0g, ln0b, B2, NN);
  // layer 1
  gemm128_kernel<<<625, 256, 0, stream>>>(B2, W1, as1, ad1, hb, als, ald);
  aggregate128_kernel<<<(NN + 3) / 4, 256, 0, stream>>>(hb, als, ald, row_ptr, csr_src,
                                                        b1, ln1g, ln1b, B2, NN);
  // layer 2
  gemm32_kernel<<<625, 256, 0, stream>>>(B2, W2, as2, ad2, h2, als, ald);
  aggregate32_kernel<<<(NN + 3) / 4, 256, 0, stream>>>(h2, als, ald, row_ptr, csr_src,
                                                       b2, ln2g, ln2b, x2, NN);
  // pool + classifier (fused)
  poolfc_kernel<<<NG, 256, 0, stream>>>(x2, batch, fc1w, fc1b, fc2w, fc2b, out, NN);
}

// Round 10
// 255.109 us; speedup vs baseline: 1.2136x; 1.0585x over previous
//
#include <hip/hip_runtime.h>
#include <hip/hip_fp16.h>
#include <math.h>

#define NN 40000
#define EE 640000
#define NG 64
#define SCAN_BLOCKS ((NN + 1023) / 1024)

__device__ __forceinline__ float eluf(float x) { return x > 0.f ? x : expm1f(x); }

typedef const __attribute__((address_space(1))) char gas_char;
typedef __attribute__((address_space(3))) char las_char;

__device__ __forceinline__ void async_copy16(void* l, const void* g) {
  __builtin_amdgcn_global_load_lds((gas_char*)g, (las_char*)l, 16, 0, 0);
}

typedef __fp16 f16x2 __attribute__((ext_vector_type(2)));
__device__ __forceinline__ unsigned packh(float lo, float hi) {  // f32x2 -> packed fp16
  f16x2 p = __builtin_amdgcn_cvt_pkrtz(lo, hi);
  union { f16x2 h; unsigned u; } c; c.h = p; return c.u;
}
__device__ __forceinline__ float hlo(unsigned p) {
  union { unsigned u; f16x2 h; } c; c.u = p; return (float)c.h.x;
}
__device__ __forceinline__ float hhi(unsigned p) {
  union { unsigned u; f16x2 h; } c; c.u = p; return (float)c.h.y;
}

__global__ void zero_int_kernel(int* __restrict__ p, int n) {
  int i = blockIdx.x * 256 + threadIdx.x;
  if (i < n) p[i] = 0;
}

__global__ void count_deg_kernel(const int* __restrict__ dst, int* __restrict__ deg, int e) {
  int i = blockIdx.x * 256 + threadIdx.x;
  if (i < e) atomicAdd(&deg[dst[i]], 1);
}

__global__ __launch_bounds__(1024) void scanA_kernel(const int* __restrict__ deg,
                                                     int* __restrict__ row_ptr,
                                                     int* __restrict__ bsum, int n) {
  __shared__ int wsum[16];
  int t = threadIdx.x, lane = t & 63, wid = t >> 6;
  int i = blockIdx.x * 1024 + t;
  int v = (i < n) ? deg[i] : 0;
#pragma unroll
  for (int off = 1; off < 64; off <<= 1) {
    int u = __shfl_up(v, off);
    if (lane >= off) v += u;
  }
  if (lane == 63) wsum[wid] = v;
  __syncthreads();
  if (t < 16) {
    int w = wsum[t];
#pragma unroll
    for (int off = 1; off < 16; off <<= 1) {
      int u = __shfl_up(w, off);
      if (t >= off) w += u;
    }
    wsum[t] = w;
  }
  __syncthreads();
  if (wid > 0) v += wsum[wid - 1];
  if (i < n) row_ptr[i + 1] = v;
  if (t == 1023) bsum[blockIdx.x] = v;
}

// scanC with inlined block-offset computation (scanB merged): each block
// sum-reduces bsum[0..blockIdx-1] in one wave (SCAN_BLOCKS=40 <= 64 lanes).
__global__ __launch_bounds__(1024) void scanC_kernel(int* __restrict__ row_ptr,
                                                     const int* __restrict__ bsum,
                                                     int* __restrict__ cursor, int n) {
  __shared__ int off_s;
  int t = threadIdx.x;
  int b = blockIdx.x;
  if (t < 64) {
    int v = (t < b && t < SCAN_BLOCKS) ? bsum[t] : 0;
#pragma unroll
    for (int m = 1; m < 64; m <<= 1) v += __shfl_xor(v, m);
    if (t == 0) off_s = v;
  }
  __syncthreads();
  int off = off_s;
  int i = b * 1024 + t;
  if (i < n) {
    int v = row_ptr[i + 1] + off;
    row_ptr[i + 1] = v;
    if (i + 1 < n) cursor[i + 1] = v;
    if (i == 0) { cursor[0] = 0; row_ptr[0] = 0; }
  }
}

__global__ void scatter_kernel(const int* __restrict__ src, const int* __restrict__ dst,
                               int* __restrict__ cursor, int* __restrict__ csr_src, int e) {
  int i = blockIdx.x * 256 + threadIdx.x;
  if (i < e) {
    int d = dst[i];
    int pos = atomicAdd(&cursor[d], 1);
    csr_src[pos] = src[i];
  }
}

// GEMM (K=128, OUT=128): h = x @ W written as PACKED FP16 pairs.
// LDS 48KB (x k-chunked dbuf 16KB + W dbuf 32KB) -> 3 blocks/CU.
__global__ __launch_bounds__(256, 3) void gemm128_kernel(
    const float* __restrict__ x, const float* __restrict__ W,
    const float* __restrict__ a_s, const float* __restrict__ a_d,
    unsigned* __restrict__ hb, float* __restrict__ als, float* __restrict__ ald)
{
  __shared__ float xs[2][64 * 32];
  __shared__ float ws[2][32 * 128];

  int t = threadIdx.x;
  int row0 = blockIdx.x * 64;
  const char* xgb = (const char*)x + (size_t)row0 * 512;

  {
    int li0 = t, li1 = t + 256;
    async_copy16((char*)xs[0] + li0 * 16, xgb + (li0 >> 3) * 512 + (li0 & 7) * 16);
    async_copy16((char*)xs[0] + li1 * 16, xgb + (li1 >> 3) * 512 + (li1 & 7) * 16);
    const char* wg = (const char*)W;
#pragma unroll
    for (int p = 0; p < 4; ++p)
      async_copy16((char*)ws[0] + p * 4096 + t * 16, wg + p * 4096 + t * 16);
  }
  __syncthreads();

  int cg = t & 31, rg = t >> 5;
  int r0 = rg * 8;
  int jlo = 2 * cg;

  float acc[8][4];
#pragma unroll
  for (int r = 0; r < 8; ++r)
#pragma unroll
    for (int c = 0; c < 4; ++c) acc[r][c] = 0.f;

  for (int ch = 0; ch < 4; ++ch) {
    if (ch < 3) {
      int b = (ch + 1) & 1;
      int li0 = t, li1 = t + 256;
      const char* xg = xgb + (ch + 1) * 128;
      async_copy16((char*)xs[b] + li0 * 16, xg + (li0 >> 3) * 512 + (li0 & 7) * 16);
      async_copy16((char*)xs[b] + li1 * 16, xg + (li1 >> 3) * 512 + (li1 & 7) * 16);
      const char* wg = (const char*)W + (size_t)(ch + 1) * 32 * 128 * 4;
#pragma unroll
      for (int p = 0; p < 4; ++p)
        async_copy16((char*)ws[b] + p * 4096 + t * 16, wg + p * 4096 + t * 16);
    }
    const float* wc = ws[ch & 1];
    const float* xc = xs[ch & 1];
#pragma unroll
    for (int kk = 0; kk < 32; kk += 4) {
      float2 wlo[4], whi[4];
#pragma unroll
      for (int q = 0; q < 4; ++q) {
        wlo[q] = *reinterpret_cast<const float2*>(&wc[(kk + q) * 128 + jlo]);
        whi[q] = *reinterpret_cast<const float2*>(&wc[(kk + q) * 128 + 64 + jlo]);
      }
#pragma unroll
      for (int r = 0; r < 8; ++r) {
        float4 xv = *reinterpret_cast<const float4*>(&xc[(r0 + r) * 32 + kk]);
        float a0 = acc[r][0], a1 = acc[r][1], a2 = acc[r][2], a3 = acc[r][3];
        a0 = fmaf(xv.x, wlo[0].x, a0); a1 = fmaf(xv.x, wlo[0].y, a1);
        a2 = fmaf(xv.x, whi[0].x, a2); a3 = fmaf(xv.x, whi[0].y, a3);
        a0 = fmaf(xv.y, wlo[1].x, a0); a1 = fmaf(xv.y, wlo[1].y, a1);
        a2 = fmaf(xv.y, whi[1].x, a2); a3 = fmaf(xv.y, whi[1].y, a3);
        a0 = fmaf(xv.z, wlo[2].x, a0); a1 = fmaf(xv.z, wlo[2].y, a1);
        a2 = fmaf(xv.z, whi[2].x, a2); a3 = fmaf(xv.z, whi[2].y, a3);
        a0 = fmaf(xv.w, wlo[3].x, a0); a1 = fmaf(xv.w, wlo[3].y, a1);
        a2 = fmaf(xv.w, whi[3].x, a2); a3 = fmaf(xv.w, whi[3].y, a3);
        acc[r][0] = a0; acc[r][1] = a1; acc[r][2] = a2; acc[r][3] = a3;
      }
    }
    __syncthreads();
  }

#pragma unroll
  for (int r = 0; r < 8; ++r) {
    uint2 pv;
    pv.x = packh(acc[r][0], acc[r][2]);
    pv.y = packh(acc[r][1], acc[r][3]);
    *reinterpret_cast<uint2*>(&hb[(size_t)(row0 + r0 + r) * 64 + jlo]) = pv;
  }

  float as0 = a_s[jlo], as1 = a_s[jlo + 1], as2 = a_s[jlo + 64], as3 = a_s[jlo + 65];
  float ad0 = a_d[jlo], ad1 = a_d[jlo + 1], ad2 = a_d[jlo + 64], ad3 = a_d[jlo + 65];
  int lane = t & 63;
#pragma unroll
  for (int r = 0; r < 8; ++r) {
    float psa = fmaf(acc[r][0], as0, acc[r][1] * as1);
    float psb = fmaf(acc[r][2], as2, acc[r][3] * as3);
    float pda = fmaf(acc[r][0], ad0, acc[r][1] * ad1);
    float pdb = fmaf(acc[r][2], ad2, acc[r][3] * ad3);
#pragma unroll
    for (int m = 1; m < 16; m <<= 1) {
      psa += __shfl_xor(psa, m); psb += __shfl_xor(psb, m);
      pda += __shfl_xor(pda, m); pdb += __shfl_xor(pdb, m);
    }
    if ((lane & 15) == 0) {
      int hA = (lane >> 4) & 1;
      size_t row = (size_t)(row0 + r0 + r);
      als[row * 4 + hA] = psa; als[row * 4 + hA + 2] = psb;
      ald[row * 4 + hA] = pda; ald[row * 4 + hA + 2] = pdb;
    }
  }
}

// GEMM (K=128, OUT=32) f32 out, fused single-head als/ald.
__global__ __launch_bounds__(256, 2) void gemm32_kernel(
    const float* __restrict__ x, const float* __restrict__ W,
    const float* __restrict__ a_s, const float* __restrict__ a_d,
    float* __restrict__ h, float* __restrict__ als, float* __restrict__ ald)
{
  __shared__ float xs[64 * 128];
  __shared__ float ws[2][32 * 32];
  int t = threadIdx.x;
  int row0 = blockIdx.x * 64;
  {
    const char* xg = (const char*)(x + (size_t)row0 * 128);
    char* xl = (char*)xs;
#pragma unroll
    for (int it = 0; it < 8; ++it)
      async_copy16(xl + it * 4096 + t * 16, xg + it * 4096 + t * 16);
  }
  async_copy16((char*)ws[0] + t * 16, (const char*)W + t * 16);
  __syncthreads();

  int cg = t & 7, rg = t >> 3;
  int r0 = rg * 2, c0 = cg * 4;
  float acc[2][4];
#pragma unroll
  for (int r = 0; r < 2; ++r)
#pragma unroll
    for (int c = 0; c < 4; ++c) acc[r][c] = 0.f;

  for (int ch = 0; ch < 4; ++ch) {
    if (ch < 3) {
      const char* wg = (const char*)W + (size_t)(ch + 1) * 32 * 32 * 4;
      async_copy16((char*)ws[(ch + 1) & 1] + t * 16, wg + t * 16);
    }
    const float* wc = ws[ch & 1];
    const float* xc = xs + ch * 32;
#pragma unroll
    for (int kk = 0; kk < 32; kk += 4) {
      float4 wv[4];
#pragma unroll
      for (int q = 0; q < 4; ++q)
        wv[q] = *reinterpret_cast<const float4*>(&wc[(kk + q) * 32 + c0]);
#pragma unroll
      for (int r = 0; r < 2; ++r) {
        float4 xv = *reinterpret_cast<const float4*>(&xc[(r0 + r) * 128 + kk]);
#pragma unroll
        for (int c = 0; c < 4; ++c) {
          float a = acc[r][c];
          a = fmaf(xv.x, (&wv[0].x)[c], a);
          a = fmaf(xv.y, (&wv[1].x)[c], a);
          a = fmaf(xv.z, (&wv[2].x)[c], a);
          a = fmaf(xv.w, (&wv[3].x)[c], a);
          acc[r][c] = a;
        }
      }
    }
    __syncthreads();
  }

#pragma unroll
  for (int r = 0; r < 2; ++r) {
    float4 hv = make_float4(acc[r][0], acc[r][1], acc[r][2], acc[r][3]);
    *reinterpret_cast<float4*>(&h[(size_t)(row0 + r0 + r) * 32 + c0]) = hv;
  }
  float asv[4], adv[4];
#pragma unroll
  for (int c = 0; c < 4; ++c) { asv[c] = a_s[c0 + c]; adv[c] = a_d[c0 + c]; }
#pragma unroll
  for (int r = 0; r < 2; ++r) {
    float ps = acc[r][0] * asv[0] + acc[r][1] * asv[1] + acc[r][2] * asv[2] + acc[r][3] * asv[3];
    float pd = acc[r][0] * adv[0] + acc[r][1] * adv[1] + acc[r][2] * adv[2] + acc[r][3] * adv[3];
#pragma unroll
    for (int m = 1; m < 8; m <<= 1) { ps += __shfl_xor(ps, m); pd += __shfl_xor(pd, m); }
    if ((t & 7) == 0) {
      als[row0 + r0 + r] = ps;
      ald[row0 + r0 + r] = pd;
    }
  }
}

// Aggregate for OUT=128. HALF-WAVE PER NODE: 8 nodes per 256-thread block.
// Lane c (=lane&31) owns features {2c,2c+1,2c+64,2c+65} of its half's node.
// Every lane iterates ALL edges of its node -> ssum is per-lane (no reduce),
// no cross-half combine; LN reduces over 32 lanes (5 steps).
__global__ __launch_bounds__(256) void aggregate128_kernel(
    const unsigned* __restrict__ hb, const float* __restrict__ als, const float* __restrict__ ald,
    const int* __restrict__ row_ptr, const int* __restrict__ csr_src,
    const float* __restrict__ bias, const float* __restrict__ ln_g, const float* __restrict__ ln_b,
    float* __restrict__ out, int n)
{
  __shared__ int s_src[4][2][32];
  __shared__ float2 s_w[4][2][32][2];
  int t = threadIdx.x, lane = t & 63, wid = t >> 6;
  int hw = lane >> 5, c = lane & 31;
  int node = blockIdx.x * 8 + wid * 2 + hw;   // N = 40000 = 5000*8 exact
  int start = row_ptr[node], end = row_ptr[node + 1];
  int deg = end - start;

  float4 adq = reinterpret_cast<const float4*>(ald)[node];
  int hsel = c >> 4;                 // head pair (hsel, hsel+2)
  float a0 = 0.f, a1 = 0.f, a2 = 0.f, a3 = 0.f;
  float ssum0 = 0.f, ssum1 = 0.f;

  if (deg <= 32) {
    int s = 0;
    float ex0 = 0.f, ex1 = 0.f, ex2 = 0.f, ex3 = 0.f;
    if (c < deg) {
      s = csr_src[start + c];
      float4 q = reinterpret_cast<const float4*>(als)[s];
      float v0 = q.x + adq.x, v1 = q.y + adq.y, v2 = q.z + adq.z, v3 = q.w + adq.w;
      v0 = v0 > 0.f ? v0 : 0.2f * v0; v1 = v1 > 0.f ? v1 : 0.2f * v1;
      v2 = v2 > 0.f ? v2 : 0.2f * v2; v3 = v3 > 0.f ? v3 : 0.2f * v3;
      ex0 = __expf(v0); ex1 = __expf(v1); ex2 = __expf(v2); ex3 = __expf(v3);
    }
    s_src[wid][hw][c] = s;
    s_w[wid][hw][c][0] = make_float2(ex0, ex2);
    s_w[wid][hw][c][1] = make_float2(ex1, ex3);

    float b0a = 0.f, b1a = 0.f, b2a = 0.f, b3a = 0.f;
    float sb0 = 0.f, sb1 = 0.f;
    int j = 0;
    for (; j + 2 <= deg; j += 2) {
      int sa = s_src[wid][hw][j];
      int sb = s_src[wid][hw][j + 1];
      uint2 ua = *reinterpret_cast<const uint2*>(&hb[(size_t)sa * 64 + 2 * c]);
      uint2 ub = *reinterpret_cast<const uint2*>(&hb[(size_t)sb * 64 + 2 * c]);
      float2 wa = s_w[wid][hw][j][hsel];
      float2 wb = s_w[wid][hw][j + 1][hsel];
      a0 = fmaf(wa.x, hlo(ua.x), a0); a1 = fmaf(wa.x, hlo(ua.y), a1);
      a2 = fmaf(wa.y, hhi(ua.x), a2); a3 = fmaf(wa.y, hhi(ua.y), a3);
      ssum0 += wa.x; ssum1 += wa.y;
      b0a = fmaf(wb.x, hlo(ub.x), b0a); b1a = fmaf(wb.x, hlo(ub.y), b1a);
      b2a = fmaf(wb.y, hhi(ub.x), b2a); b3a = fmaf(wb.y, hhi(ub.y), b3a);
      sb0 += wb.x; sb1 += wb.y;
    }
    if (j < deg) {
      int sa = s_src[wid][hw][j];
      uint2 ua = *reinterpret_cast<const uint2*>(&hb[(size_t)sa * 64 + 2 * c]);
      float2 wa = s_w[wid][hw][j][hsel];
      a0 = fmaf(wa.x, hlo(ua.x), a0); a1 = fmaf(wa.x, hlo(ua.y), a1);
      a2 = fmaf(wa.y, hhi(ua.x), a2); a3 = fmaf(wa.y, hhi(ua.y), a3);
      ssum0 += wa.x; ssum1 += wa.y;
    }
    a0 += b0a; a1 += b1a; a2 += b2a; a3 += b3a;
    ssum0 += sb0; ssum1 += sb1;
  } else {
    // chunked fallback (deg > 32: rare at avg degree 16)
    for (int eb = 0; eb < deg; eb += 32) {
      int s = 0;
      float ex0 = 0.f, ex1 = 0.f, ex2 = 0.f, ex3 = 0.f;
      if (eb + c < deg) {
        s = csr_src[start + eb + c];
        float4 q = reinterpret_cast<const float4*>(als)[s];
        float v0 = q.x + adq.x, v1 = q.y + adq.y, v2 = q.z + adq.z, v3 = q.w + adq.w;
        v0 = v0 > 0.f ? v0 : 0.2f * v0; v1 = v1 > 0.f ? v1 : 0.2f * v1;
        v2 = v2 > 0.f ? v2 : 0.2f * v2; v3 = v3 > 0.f ? v3 : 0.2f * v3;
        ex0 = __expf(v0); ex1 = __expf(v1); ex2 = __expf(v2); ex3 = __expf(v3);
      }
      s_src[wid][hw][c] = s;
      s_w[wid][hw][c][0] = make_float2(ex0, ex2);
      s_w[wid][hw][c][1] = make_float2(ex1, ex3);
      int cnt = deg - eb; if (cnt > 32) cnt = 32;
      for (int j = 0; j < cnt; ++j) {
        int sj = s_src[wid][hw][j];
        uint2 u = *reinterpret_cast<const uint2*>(&hb[(size_t)sj * 64 + 2 * c]);
        float2 w = s_w[wid][hw][j][hsel];
        a0 = fmaf(w.x, hlo(u.x), a0); a1 = fmaf(w.x, hlo(u.y), a1);
        a2 = fmaf(w.y, hhi(u.x), a2); a3 = fmaf(w.y, hhi(u.y), a3);
        ssum0 += w.x; ssum1 += w.y;
      }
    }
  }

  float2 blo = *reinterpret_cast<const float2*>(&bias[2 * c]);
  float2 bhi = *reinterpret_cast<const float2*>(&bias[2 * c + 64]);
  float is0 = 1.f / (ssum0 + 1e-16f), is1 = 1.f / (ssum1 + 1e-16f);
  float o0 = a0 * is0 + blo.x;
  float o1 = a1 * is0 + blo.y;
  float o2 = a2 * is1 + bhi.x;
  float o3 = a3 * is1 + bhi.y;
  // LN over the half-wave (32 lanes x 4 features = 128, each counted once)
  float red = o0 + o1 + o2 + o3;
  float sq2 = o0 * o0 + o1 * o1 + o2 * o2 + o3 * o3;
#pragma unroll
  for (int m = 1; m < 32; m <<= 1) {
    red += __shfl_xor(red, m);
    sq2 += __shfl_xor(sq2, m);
  }
  float mu = red * (1.f / 128.f);
  float var = sq2 * (1.f / 128.f) - mu * mu;
  float rstd = rsqrtf(var + 1e-5f);
  float2 glo = *reinterpret_cast<const float2*>(&ln_g[2 * c]);
  float2 ghi = *reinterpret_cast<const float2*>(&ln_g[2 * c + 64]);
  float2 bl2 = *reinterpret_cast<const float2*>(&ln_b[2 * c]);
  float2 bh2 = *reinterpret_cast<const float2*>(&ln_b[2 * c + 64]);
  float2 ylo, yhi;
  ylo.x = eluf((o0 - mu) * rstd * glo.x + bl2.x);
  ylo.y = eluf((o1 - mu) * rstd * glo.y + bl2.y);
  yhi.x = eluf((o2 - mu) * rstd * ghi.x + bh2.x);
  yhi.y = eluf((o3 - mu) * rstd * ghi.y + bh2.y);
  *reinterpret_cast<float2*>(&out[(size_t)node * 128 + 2 * c]) = ylo;
  *reinterpret_cast<float2*>(&out[(size_t)node * 128 + 64 + 2 * c]) = yhi;
}

// Aggregate for OUT=32. HALF-WAVE PER NODE: lane c owns feature c.
__global__ __launch_bounds__(256) void aggregate32_kernel(
    const float* __restrict__ h, const float* __restrict__ als, const float* __restrict__ ald,
    const int* __restrict__ row_ptr, const int* __restrict__ csr_src,
    const float* __restrict__ bias, const float* __restrict__ ln_g, const float* __restrict__ ln_b,
    float* __restrict__ out, int n)
{
  __shared__ int s_src[4][2][32];
  __shared__ float s_ex[4][2][32];
  int t = threadIdx.x, lane = t & 63, wid = t >> 6;
  int hw = lane >> 5, c = lane & 31;
  int node = blockIdx.x * 8 + wid * 2 + hw;   // exact fit
  int start = row_ptr[node], end = row_ptr[node + 1];
  int deg = end - start;
  float adl = ald[node];
  float acc0 = 0.f, ssum = 0.f;

  if (deg <= 32) {
    int s = 0; float ex = 0.f;
    if (c < deg) {
      s = csr_src[start + c];
      float v = als[s] + adl;
      v = v > 0.f ? v : 0.2f * v;
      ex = __expf(v);
    }
    s_src[wid][hw][c] = s;
    s_ex[wid][hw][c] = ex;

    float acc1 = 0.f, ssum1 = 0.f;
    int j = 0;
    for (; j + 2 <= deg; j += 2) {
      int sa = s_src[wid][hw][j];
      int sb = s_src[wid][hw][j + 1];
      float ha = h[(size_t)sa * 32 + c];
      float hbv = h[(size_t)sb * 32 + c];
      float wa = s_ex[wid][hw][j];
      float wb = s_ex[wid][hw][j + 1];
      acc0 = fmaf(wa, ha, acc0); ssum += wa;
      acc1 = fmaf(wb, hbv, acc1); ssum1 += wb;
    }
    if (j < deg) {
      float wa = s_ex[wid][hw][j];
      acc0 = fmaf(wa, h[(size_t)s_src[wid][hw][j] * 32 + c], acc0);
      ssum += wa;
    }
    acc0 += acc1; ssum += ssum1;
  } else {
    for (int eb = 0; eb < deg; eb += 32) {
      int s = 0; float ex = 0.f;
      if (eb + c < deg) {
        s = csr_src[start + eb + c];
        float v = als[s] + adl;
        v = v > 0.f ? v : 0.2f * v;
        ex = __expf(v);
      }
      s_src[wid][hw][c] = s;
      s_ex[wid][hw][c] = ex;
      int cnt = deg - eb; if (cnt > 32) cnt = 32;
      for (int j = 0; j < cnt; ++j) {
        float w = s_ex[wid][hw][j];
        acc0 = fmaf(w, h[(size_t)s_src[wid][hw][j] * 32 + c], acc0);
        ssum += w;
      }
    }
  }

  float o0 = acc0 / (ssum + 1e-16f) + bias[c];
  float red = o0, sq2 = o0 * o0;
#pragma unroll
  for (int m = 1; m < 32; m <<= 1) {
    red += __shfl_xor(red, m);
    sq2 += __shfl_xor(sq2, m);
  }
  float mu = red * (1.f / 32.f);
  float var = sq2 * (1.f / 32.f) - mu * mu;
  float rstd = rsqrtf(var + 1e-5f);
  float y0 = (o0 - mu) * rstd * ln_g[c] + ln_b[c];
  out[(size_t)node * 32 + c] = eluf(y0);
}

__device__ __forceinline__ int lower_bound_dev(const int* a, int n, int key) {
  int lo = 0, hi = n;
  while (lo < hi) { int mid = (lo + hi) >> 1; if (a[mid] < key) lo = mid + 1; else hi = mid; }
  return lo;
}

// Fused global mean-pool + 2-layer classifier: one block per group.
__global__ __launch_bounds__(256) void poolfc_kernel(
    const float* __restrict__ x2, const int* __restrict__ batch,
    const float* __restrict__ fc1w, const float* __restrict__ fc1b,
    const float* __restrict__ fc2w, const float* __restrict__ fc2b,
    float* __restrict__ out, int n)
{
  int g = blockIdx.x;
  int lo = lower_bound_dev(batch, n, g);
  int hi = lower_bound_dev(batch, n, g + 1);
  int t = threadIdx.x;
  int c = t & 31, r = t >> 5;
  float acc = 0.f;
  for (int i = lo + r; i < hi; i += 8) acc += x2[(size_t)i * 32 + c];
  __shared__ float red[8][32];
  __shared__ float hgl[32];
  __shared__ float zl[16];
  red[r][c] = acc;
  __syncthreads();
  if (r == 0) {
    float s = 0.f;
#pragma unroll
    for (int k = 0; k < 8; ++k) s += red[k][c];
    float cnt = (float)(hi - lo);
    hgl[c] = s / fmaxf(cnt, 1.f);
  }
  __syncthreads();
  if (t < 16) {
    float a = fc1b[t];
#pragma unroll
    for (int k = 0; k < 32; ++k) a = fmaf(hgl[k], fc1w[k * 16 + t], a);
    zl[t] = fmaxf(a, 0.f);
  }
  __syncthreads();
  if (t < 2) {
    float a = fc2b[t];
#pragma unroll
    for (int j = 0; j < 16; ++j) a = fmaf(zl[j], fc2w[j * 2 + t], a);
    out[g * 2 + t] = a;
  }
}

extern "C" void kernel_launch(void* const* d_in, const int* in_sizes, int n_in,
                              void* d_out, int out_size, void* d_ws, size_t ws_size,
                              hipStream_t stream) {
  const float* x    = (const float*)d_in[0];
  const int*   ei   = (const int*)d_in[1];
  const int*   batch= (const int*)d_in[2];
  const float* W0   = (const float*)d_in[3];
  const float* as0  = (const float*)d_in[4];
  const float* ad0  = (const float*)d_in[5];
  const float* b0   = (const float*)d_in[6];
  const float* ln0g = (const float*)d_in[7];
  const float* ln0b = (const float*)d_in[8];
  const float* W1   = (const float*)d_in[9];
  const float* as1  = (const float*)d_in[10];
  const float* ad1  = (const float*)d_in[11];
  const float* b1   = (const float*)d_in[12];
  const float* ln1g = (const float*)d_in[13];
  const float* ln1b = (const float*)d_in[14];
  const float* W2   = (const float*)d_in[15];
  const float* as2  = (const float*)d_in[16];
  const float* ad2  = (const float*)d_in[17];
  const float* b2   = (const float*)d_in[18];
  const float* ln2g = (const float*)d_in[19];
  const float* ln2b = (const float*)d_in[20];
  const float* fc1w = (const float*)d_in[21];
  const float* fc1b = (const float*)d_in[22];
  const float* fc2w = (const float*)d_in[23];
  const float* fc2b = (const float*)d_in[24];
  float* out = (float*)d_out;

  const int* srce = ei;
  const int* dste = ei + EE;

  unsigned* hb = (unsigned*)d_ws;              // N*64 packed fp16 pairs
  float* B2  = (float*)(hb + (size_t)NN * 64); // N*128
  float* als = B2 + (size_t)NN * 128;          // N*4
  float* ald = als + (size_t)NN * 4;           // N*4
  float* h2  = ald + (size_t)NN * 4;           // N*32
  float* x2  = h2 + (size_t)NN * 32;           // N*32
  int* deg      = (int*)(x2 + (size_t)NN * 32);// N
  int* row_ptr  = deg + NN;                    // N+1
  int* cursor   = row_ptr + NN + 1;            // N
  int* csr_src  = cursor + NN;                 // E
  int* bsum     = csr_src + EE;                // SCAN_BLOCKS

  // CSR build (shared by all 3 layers)
  zero_int_kernel<<<(NN + 255) / 256, 256, 0, stream>>>(deg, NN);
  count_deg_kernel<<<(EE + 255) / 256, 256, 0, stream>>>(dste, deg, EE);
  scanA_kernel<<<SCAN_BLOCKS, 1024, 0, stream>>>(deg, row_ptr, bsum, NN);
  scanC_kernel<<<SCAN_BLOCKS, 1024, 0, stream>>>(row_ptr, bsum, cursor, NN);
  scatter_kernel<<<(EE + 255) / 256, 256, 0, stream>>>(srce, dste, cursor, csr_src, EE);

  // layer 0
  gemm128_kernel<<<625, 256, 0, stream>>>(x, W0, as0, ad0, hb, als, ald);
  aggregate128_kernel<<<NN / 8, 256, 0, stream>>>(hb, als, ald, row_ptr, csr_src,
                                                  b0, ln0g, ln0b, B2, NN);
  // layer 1
  gemm128_kernel<<<625, 256, 0, stream>>>(B2, W1, as1, ad1, hb, als, ald);
  aggregate128_kernel<<<NN / 8, 256, 0, stream>>>(hb, als, ald, row_ptr, csr_src,
                                                  b1, ln1g, ln1b, B2, NN);
  // layer 2
  gemm32_kernel<<<625, 256, 0, stream>>>(B2, W2, as2, ad2, h2, als, ald);
  aggregate32_kernel<<<NN / 8, 256, 0, stream>>>(h2, als, ald, row_ptr, csr_src,
                                                 b2, ln2g, ln2b, x2, NN);
  // pool + classifier (fused)
  poolfc_kernel<<<NG, 256, 0, stream>>>(x2, batch, fc1w, fc1b, fc2w, fc2b, out, NN);
}